// Round 9
// baseline (159.644 us; speedup 1.0000x reference)
//
#include <hip/hip_runtime.h>
#include <cstdint>
#include <cstddef>

// ---------------- problem constants ----------------
#define NIMG   8
#define NPROP  2000
#define NCLS   91
#define NFG    90
#define NROW   (NIMG * NPROP)      // 16000
#define TOPK   2048
#define DETS   100
#define CKCAP  32768
#define KREGS  12                  // register-resident keys/thread (12*1024=12288)
#define CLSCAP2 256                // per-class candidate cap (E[n]~23, 256 is ~40 sigma)

#define IMG_Wf 1333.0f
#define IMG_Hf 800.0f
#define SCORE_TH 0.05f
#define MINSZ    0.01f
#define NMS_TH   0.5f
#define CLIPV    4.135166556742356f   // log(1000/16) rounded to f32
#define ORD_NEG1 0x407FFFFFu          // ford(-1.0f)
#define PADKEY   (((ull)ORD_NEG1 << 32) | 0xFFFFFFFFull)

typedef unsigned long long ull;

// ---------------- workspace layout (bytes) ----------------
static const size_t OFF_CNT   = 0;                                   // 2048 (zeroed)
static const size_t OFF_VBM   = 4096;                                // 16000*2*8
static const size_t OFF_CK    = 262144;                              // 8*32768*8
static const size_t OFF_CBOX  = OFF_CK   + (size_t)NIMG*CKCAP*8;     // 8*2048*16
static const size_t OFF_CSCOR = OFF_CBOX + (size_t)NIMG*TOPK*16;     // 8*2048*4
static const size_t OFF_CLAB  = OFF_CSCOR+ (size_t)NIMG*TOPK*4;      // 8*2048*4

// ---------------- helpers ----------------
__device__ __forceinline__ unsigned ford(float f) {
    unsigned u = __float_as_uint(f);
    return (u & 0x80000000u) ? ~u : (u | 0x80000000u);
}
__device__ __forceinline__ float fordinv(unsigned x) {
    return (x & 0x80000000u) ? __uint_as_float(x & 0x7FFFFFFFu)
                             : __uint_as_float(~x);
}

// exact op-for-op mirror of reference _decode + clip (no FMA contraction)
__device__ __forceinline__ float4 decode_clip(float4 p, float4 r) {
    float w  = __fsub_rn(p.z, p.x);
    float h  = __fsub_rn(p.w, p.y);
    float cx = __fadd_rn(p.x, __fmul_rn(0.5f, w));
    float cy = __fadd_rn(p.y, __fmul_rn(0.5f, h));
    float dx = __fdiv_rn(r.x, 10.0f);
    float dy = __fdiv_rn(r.y, 10.0f);
    float dw = fminf(__fdiv_rn(r.z, 5.0f), CLIPV);
    float dh = fminf(__fdiv_rn(r.w, 5.0f), CLIPV);
    float pcx = __fadd_rn(__fmul_rn(dx, w), cx);
    float pcy = __fadd_rn(__fmul_rn(dy, h), cy);
    float pw  = __fmul_rn(expf(dw), w);
    float ph  = __fmul_rn(expf(dh), h);
    float x1 = __fsub_rn(pcx, __fmul_rn(0.5f, pw));
    float y1 = __fsub_rn(pcy, __fmul_rn(0.5f, ph));
    float x2 = __fadd_rn(pcx, __fmul_rn(0.5f, pw));
    float y2 = __fadd_rn(pcy, __fmul_rn(0.5f, ph));
    float4 o;
    o.x = fminf(fmaxf(x1, 0.0f), IMG_Wf);
    o.y = fminf(fmaxf(y1, 0.0f), IMG_Hf);
    o.z = fminf(fmaxf(x2, 0.0f), IMG_Wf);
    o.w = fminf(fmaxf(y2, 0.0f), IMG_Hf);
    return o;
}

// bitonic wave-local phase steps (j = jmax..2 via shfl, then j=1 in-thread).
__device__ __forceinline__ void wl_phase(ull& a, ull& b, int l, int base,
                                         int k, int jmax) {
    bool desc = ((base & k) == 0);
    for (int j = jmax; j >= 2; j >>= 1) {
        int pl = l ^ (j >> 1);
        bool lower = ((base & j) == 0);
        ull pa = __shfl(a, pl), pb = __shfl(b, pl);
        bool km = (desc == lower);
        ull na = km ? (a > pa ? a : pa) : (a < pa ? a : pa);
        ull nb = km ? (b > pb ? b : pb) : (b < pb ? b : pb);
        a = na; b = nb;
    }
    ull mx = a > b ? a : b, mn = a > b ? b : a;
    a = desc ? mx : mn; b = desc ? mn : mx;
}

// ============ kernel A: softmax + decode + valid -> compacted keys + row bitmap ============
__global__ __launch_bounds__(1024) void kA(const float* __restrict__ logits,
                                           const float* __restrict__ reg,
                                           const float* __restrict__ props,
                                           ull* __restrict__ ck,
                                           int* __restrict__ cntv,
                                           ull* __restrict__ vbm2) {
    int warp = threadIdx.x >> 6;
    int lane = threadIdx.x & 63;
    int row  = blockIdx.x * 16 + warp;
    int b = row / NPROP;                 // uniform within block
    int n = row - b * NPROP;
    const float* lrow = logits + (size_t)row * NCLS;

    float xa = lrow[lane];
    float xb = (lane < 27) ? lrow[64 + lane] : -INFINITY;
    float mx = fmaxf(xa, xb);
    #pragma unroll
    for (int o = 32; o; o >>= 1) mx = fmaxf(mx, __shfl_xor(mx, o));
    float ea = expf(__fsub_rn(xa, mx));
    float eb = (lane < 27) ? expf(__fsub_rn(xb, mx)) : 0.0f;
    float s  = __fadd_rn(ea, eb);
    #pragma unroll
    for (int o = 32; o; o >>= 1) s = __fadd_rn(s, __shfl_xor(s, o));

    const float4 p = *reinterpret_cast<const float4*>(props + (size_t)row * 4);

    __shared__ int sCnt[32];
    __shared__ int sExc[32];
    __shared__ int sBase;

    ull rowmask[2];
    bool validA[2];
    ull keyA[2];
    #pragma unroll
    for (int it = 0; it < 2; ++it) {
        int c = (it == 0) ? (1 + lane) : (65 + lane);
        bool active = (it == 0) ? true : (lane < 26);
        bool valid = false;
        ull key = 0;
        if (active) {
            float lg = lrow[c];
            float score = __fdiv_rn(expf(__fsub_rn(lg, mx)), s);
            float4 r4 = *reinterpret_cast<const float4*>(
                reg + ((size_t)row * NCLS + c) * 4);
            float4 bx = decode_clip(p, r4);
            float bw = __fsub_rn(bx.z, bx.x);
            float bh = __fsub_rn(bx.w, bx.y);
            valid = (score > SCORE_TH) && (bw >= MINSZ) && (bh >= MINSZ);
            int offidx = n * NFG + (c - 1);
            key = ((ull)ford(score) << 32) |
                  (ull)(0xFFFFFFFFu - (unsigned)offidx);
        }
        ull bal = __ballot(valid);
        rowmask[it] = bal;
        validA[it] = valid;
        keyA[it] = key;
        if (lane == 0) sCnt[warp * 2 + it] = __popcll(bal);
    }
    __syncthreads();
    if (warp == 0) {
        int c = (lane < 32) ? sCnt[lane] : 0;
        int p2 = c;
        #pragma unroll
        for (int o = 1; o < 32; o <<= 1) {
            int v = __shfl_up(p2, o);
            if (lane >= o) p2 += v;
        }
        if (lane == 31) sBase = atomicAdd(&cntv[b * 64], p2);
        if (lane < 32) sExc[lane] = p2 - c;
    }
    __syncthreads();
    int base = sBase;
    #pragma unroll
    for (int it = 0; it < 2; ++it) {
        if (validA[it]) {
            int slot = base + sExc[warp * 2 + it] +
                       __popcll(rowmask[it] & ((1ull << lane) - 1ull));
            if (slot < CKCAP)
                ck[(size_t)b * CKCAP + slot] = keyA[it];
        }
    }
    if (lane == 0) {
        vbm2[(size_t)row * 2]     = rowmask[0];
        vbm2[(size_t)row * 2 + 1] = rowmask[1];
    }
}

// ============ kernel B: select + sort + decode + bucket + per-class NMS + emit ============
// LDS overlay (82 KB): [0,16K)=sk | later sbox lo; [16K,32K)=histw | later sbox hi;
// [32K,40K)=rex | later sar2; [40K,44K)=ssx2; [44K,67.2K)=clsbm(33-stride);
// [67.2K,78.8K)=wpfx(33-stride)
__global__ __launch_bounds__(1024) void kB(const ull* __restrict__ ck,
                                           const int* __restrict__ cntv,
                                           const ull* __restrict__ vbm2,
                                           const float* __restrict__ reg,
                                           const float* __restrict__ props,
                                           float4* __restrict__ cbox,
                                           float* __restrict__ cscore,
                                           int* __restrict__ clabel,
                                           float* __restrict__ out) {
    int b = blockIdx.x;
    int tid = threadIdx.x;
    int lane = tid & 63, warp = tid >> 6;
    __shared__ __align__(16) char smem[80704];
    ull*      sk    = (ull*)smem;
    unsigned* histw = (unsigned*)(smem + 16384);
    int*      rex   = (int*)(smem + 32768);
    float4*   sbox  = (float4*)smem;
    float*    sar2  = (float*)(smem + 32768);
    unsigned short* ssx2 = (unsigned short*)(smem + 40960);
    ull*      clsbm = (ull*)(smem + 45056);
    unsigned* wpfx  = (unsigned*)(smem + 68816);
    __shared__ unsigned wtot4[4];
    __shared__ ull sP;
    __shared__ int sRem, sCnt, sDone;
    __shared__ ull sVWk[32];         // keep bitmap (LDS-resident)
    __shared__ float sMax[16];
    __shared__ float sM1;
    __shared__ int wsum[16];
    __shared__ int ccnt[96], coff[96];

    if (tid < 32) sVWk[tid] = 0ull;

    int cnt = cntv[b * 64];
    if (cnt > CKCAP) cnt = CKCAP;
    const ull* K = ck + (size_t)b * CKCAP;

    if (cnt >= TOPK) {
        // ---- load keys into registers (coalesced, once) ----
        ull kreg[KREGS];
        #pragma unroll
        for (int r = 0; r < KREGS; ++r) {
            int i = tid + (r << 10);
            kreg[r] = (i < cnt) ? K[i] : 0ull;
        }
        // ---- 8x8-bit radix select with short-circuit (keys distinct) ----
        ull P = 0; int rem = TOPK;
        for (int pass = 7; pass >= 0; --pass) {
            int sh = pass * 8;
            *reinterpret_cast<uint4*>(&histw[tid * 4]) = make_uint4(0, 0, 0, 0);
            __syncthreads();
            ull pmask = (pass == 7) ? 0ull : (~0ull << (sh + 8));
            unsigned* hw = &histw[warp << 8];
            #pragma unroll
            for (int r = 0; r < KREGS; ++r) {
                int i = tid + (r << 10);
                if (i < cnt && (kreg[r] & pmask) == P)
                    atomicAdd(&hw[(unsigned)(kreg[r] >> sh) & 255u], 1u);
            }
            for (int i = (KREGS << 10) + tid; i < cnt; i += 1024) {   // rare tail
                ull k2 = K[i];
                if ((k2 & pmask) == P)
                    atomicAdd(&hw[(unsigned)(k2 >> sh) & 255u], 1u);
            }
            __syncthreads();
            unsigned x = 0, pfx = 0;
            if (tid < 256) {
                int d = 255 - tid;
                #pragma unroll
                for (int w = 0; w < 16; ++w) x += histw[(w << 8) + d];
                pfx = x;
                #pragma unroll
                for (int o = 1; o < 64; o <<= 1) {
                    unsigned v = __shfl_up(pfx, o);
                    if (lane >= o) pfx += v;
                }
                if (lane == 63) wtot4[tid >> 6] = pfx;
            }
            __syncthreads();
            if (tid < 256) {
                int d = 255 - tid;
                int ws = tid >> 6;
                unsigned add = 0;
                if (ws > 0) add += wtot4[0];
                if (ws > 1) add += wtot4[1];
                if (ws > 2) add += wtot4[2];
                unsigned pi   = pfx + add;    // suffixIncl(d)
                unsigned excl = pi - x;       // suffixExcl(d)
                if (x && excl < (unsigned)rem && pi >= (unsigned)rem) {
                    sP = P | ((ull)(unsigned)d << sh);
                    int nr = rem - (int)excl;
                    sRem = nr;
                    sDone = ((int)x == nr) ? 1 : 0;   // entire bin selected -> exact
                }
            }
            __syncthreads();
            P = sP; rem = sRem;
            if (sDone) break;      // threshold exact with low bits zero
        }
        if (tid == 0) sCnt = 0;
        __syncthreads();
        // ---- wave-aggregated compaction from registers ----
        #pragma unroll
        for (int r = 0; r < KREGS; ++r) {
            int i = tid + (r << 10);
            bool sel = (i < cnt) && (kreg[r] >= P);
            ull bal = __ballot(sel);
            int cw = __popcll(bal);
            if (cw) {
                int ldr = __ffsll((long long)bal) - 1;
                int bw = 0;
                if (lane == ldr) bw = atomicAdd(&sCnt, cw);
                bw = __shfl(bw, ldr);
                if (sel) {
                    int pos = bw + __popcll(bal & ((1ull << lane) - 1ull));
                    if (pos < TOPK) sk[pos] = kreg[r];
                }
            }
        }
        for (int i = (KREGS << 10) + tid; i < cnt; i += 1024) {       // rare tail
            ull k2 = K[i];
            bool sel = (k2 >= P);
            ull bal = __ballot(sel);
            int cw = __popcll(bal);
            if (cw) {
                int ldr = __ffsll((long long)bal) - 1;
                int bw = 0;
                if (lane == ldr) bw = atomicAdd(&sCnt, cw);
                bw = __shfl(bw, ldr);
                if (sel) {
                    int pos = bw + __popcll(bal & ((1ull << lane) - 1ull));
                    if (pos < TOPK) sk[pos] = k2;
                }
            }
        }
        __syncthreads();
        int fc = sCnt;
        for (int i = fc + tid; i < TOPK; i += 1024) sk[i] = PADKEY;
    } else {
        // take all valid + fill with smallest-index invalid (score -1, ascending idx)
        for (int i = tid; i < cnt; i += 1024) sk[i] = K[i];
        int F = TOPK - cnt;
        const ull* V = vbm2 + (size_t)b * NPROP * 2;
        int r0 = 2 * tid, r1 = r0 + 1;
        int v0 = 0, v1 = 0;
        if (r0 < NPROP) v0 = NFG - __popcll(V[r0 * 2]) - __popcll(V[r0 * 2 + 1]);
        if (r1 < NPROP) v1 = NFG - __popcll(V[r1 * 2]) - __popcll(V[r1 * 2 + 1]);
        int s2 = v0 + v1;
        int pfx = s2;
        #pragma unroll
        for (int o = 1; o < 64; o <<= 1) {
            int t = __shfl_up(pfx, o);
            if (lane >= o) pfx += t;
        }
        if (lane == 63) wsum[warp] = pfx;
        __syncthreads();
        if (tid == 0) {
            int a = 0;
            for (int w = 0; w < 16; ++w) { int t = wsum[w]; wsum[w] = a; a += t; }
        }
        __syncthreads();
        int excl = pfx - s2 + wsum[warp];
        if (r0 < NPROP) rex[r0] = excl;
        if (r1 < NPROP) rex[r1] = excl + v0;
        __syncthreads();
        for (int r = tid; r < NPROP; r += 1024) {
            int e = rex[r];
            if (e < F) {
                ull m0 = V[r * 2], m1 = V[r * 2 + 1];
                int rank = e;
                ull inv = ~m0;
                while (inv && rank < F) {
                    int cb = __builtin_ctzll(inv); inv &= inv - 1;
                    unsigned idx = (unsigned)(r * NFG + cb);
                    sk[cnt + rank] = ((ull)ORD_NEG1 << 32) | (ull)(0xFFFFFFFFu - idx);
                    ++rank;
                }
                inv = (~m1) & ((1ull << 26) - 1ull);
                while (inv && rank < F) {
                    int cb = __builtin_ctzll(inv); inv &= inv - 1;
                    unsigned idx = (unsigned)(r * NFG + 64 + cb);
                    sk[cnt + rank] = ((ull)ORD_NEG1 << 32) | (ull)(0xFFFFFFFFu - idx);
                    ++rank;
                }
            }
        }
    }
    __syncthreads();

    // ---- hybrid bitonic sort, descending (pair-indexed LDS steps) ----
    {
        int ebase = warp * 128 + lane * 2;
        ulonglong2 v = *reinterpret_cast<ulonglong2*>(&sk[ebase]);
        ull a = v.x, bb = v.y;
        #pragma unroll
        for (int k = 2; k <= 128; k <<= 1)
            wl_phase(a, bb, lane, ebase, k, (k >> 1) < 64 ? (k >> 1) : 64);
        v.x = a; v.y = bb;
        *reinterpret_cast<ulonglong2*>(&sk[ebase]) = v;
        for (int k = 256; k <= TOPK; k <<= 1) {
            for (int j = k >> 1; j >= 128; j >>= 1) {
                __syncthreads();
                int i = ((tid & ~(j - 1)) << 1) | (tid & (j - 1));
                int ij = i | j;
                ull x1 = sk[i], x2 = sk[ij];
                bool descSeg = ((i & k) == 0);
                if ((x1 < x2) == descSeg) { sk[i] = x2; sk[ij] = x1; }
            }
            __syncthreads();
            v = *reinterpret_cast<ulonglong2*>(&sk[ebase]);
            a = v.x; bb = v.y;
            wl_phase(a, bb, lane, ebase, k, 64);
            v.x = a; v.y = bb;
            *reinterpret_cast<ulonglong2*>(&sk[ebase]) = v;
        }
    }
    __syncthreads();

    // ---- epilogue: decode candidates (sk -> registers; sk dead after this) ----
    float lmax = 0.0f;
    float4 myb[2]; int myl[2]; float mys[2]; bool vkA[2];
    #pragma unroll
    for (int r = 0; r < 2; ++r) {
        int sidx = tid + r * 1024;
        ull k = sk[sidx];
        unsigned idx = 0xFFFFFFFFu - (unsigned)(k & 0xFFFFFFFFu);
        float score = fordinv((unsigned)(k >> 32));
        int n = (int)(idx / NFG), c = (int)(idx % NFG);     // label = c+1
        int row = b * NPROP + n;
        float4 p  = *reinterpret_cast<const float4*>(props + (size_t)row * 4);
        float4 r4 = *reinterpret_cast<const float4*>(
            reg + ((size_t)row * NCLS + (c + 1)) * 4);
        float4 bx = decode_clip(p, r4);
        myb[r] = bx; myl[r] = c + 1; mys[r] = score;
        vkA[r] = (((unsigned)(k >> 32)) != ORD_NEG1);
        lmax = fmaxf(lmax, fmaxf(fmaxf(bx.x, bx.y), fmaxf(bx.z, bx.w)));
    }
    #pragma unroll
    for (int o = 32; o; o >>= 1) lmax = fmaxf(lmax, __shfl_xor(lmax, o));
    if ((tid & 63) == 0) sMax[tid >> 6] = lmax;
    __syncthreads();
    if (tid == 0) {
        float v = sMax[0];
        for (int i = 1; i < 16; ++i) v = fmaxf(v, sMax[i]);
        sM1 = __fadd_rn(v, 1.0f);            // jnp.max(cand_boxes) + 1.0
    }
    __syncthreads();
    float m1 = sM1;
    float4 obA[2]; float arA[2];
    #pragma unroll
    for (int r = 0; r < 2; ++r) {
        int sidx = tid + r * 1024;
        float off = __fmul_rn((float)myl[r], m1);
        float4 ob;
        ob.x = __fadd_rn(myb[r].x, off);
        ob.y = __fadd_rn(myb[r].y, off);
        ob.z = __fadd_rn(myb[r].z, off);
        ob.w = __fadd_rn(myb[r].w, off);
        float area = __fmul_rn(__fsub_rn(ob.z, ob.x), __fsub_rn(ob.w, ob.y));
        obA[r] = ob; arA[r] = area;
        int g = b * TOPK + sidx;
        cbox[g] = myb[r]; cscore[g] = mys[r]; clabel[g] = myl[r];
    }

    // ---- per-class bucketing (33-stride bitmaps; exact within-class order) ----
    for (int i = tid; i < NFG * 33; i += 1024) clsbm[i] = 0ull;
    __syncthreads();
    #pragma unroll
    for (int r = 0; r < 2; ++r) {
        int sidx = tid + (r << 10);
        if (vkA[r])
            atomicOr(&clsbm[(myl[r] - 1) * 33 + (sidx >> 6)], 1ull << (sidx & 63));
    }
    __syncthreads();
    if (tid < NFG) {
        unsigned run = 0;
        for (int w = 0; w < 32; ++w) {
            wpfx[tid * 33 + w] = run;
            run += (unsigned)__popcll(clsbm[tid * 33 + w]);
        }
        ccnt[tid] = (int)run;
    }
    __syncthreads();
    if (tid == 0) {
        int a = 0;
        for (int c2 = 0; c2 < NFG; ++c2) { coff[c2] = a; a += ccnt[c2]; }
    }
    __syncthreads();   // also: last read of sk/histw/rex regions was before here
    #pragma unroll
    for (int r = 0; r < 2; ++r) {
        int sidx = tid + (r << 10);
        if (vkA[r]) {
            int cl = myl[r] - 1;
            int rank = (int)wpfx[cl * 33 + (sidx >> 6)] +
                       (int)__popcll(clsbm[cl * 33 + (sidx >> 6)] &
                                     ((1ull << (sidx & 63)) - 1ull));
            int slot = coff[cl] + rank;
            sbox[slot] = obA[r]; sar2[slot] = arA[r];
            ssx2[slot] = (unsigned short)sidx;
        }
    }
    __syncthreads();

    // ---- per-class greedy NMS (wave w handles classes w, w+16, ...) ----
    #pragma unroll 1
    for (int c = warp; c < NFG; c += 16) {
        int n = ccnt[c];
        if (n <= 0) continue;
        if (n > CLSCAP2) n = CLSCAP2;
        int base = coff[c];
        if (n <= 64) {
            float4 b0; float a0 = 0.0f;
            if (lane < n) { b0 = sbox[base + lane]; a0 = sar2[base + lane]; }
            ull alive = (n == 64) ? ~0ull : ((1ull << n) - 1ull);
            #pragma unroll 1
            for (int i = 0; i < n; ++i) {
                if (!((alive >> i) & 1ull)) continue;
                float bix = __shfl(b0.x, i), biy = __shfl(b0.y, i);
                float biz = __shfl(b0.z, i), biw = __shfl(b0.w, i);
                float ai2 = __shfl(a0, i);
                bool sup = false;
                if (lane < n && lane > i) {
                    float lt0 = fmaxf(bix, b0.x), lt1 = fmaxf(biy, b0.y);
                    float rb0 = fminf(biz, b0.z), rb1 = fminf(biw, b0.w);
                    float w0 = fmaxf(__fsub_rn(rb0, lt0), 0.0f);
                    float w1 = fmaxf(__fsub_rn(rb1, lt1), 0.0f);
                    float inter = __fmul_rn(w0, w1);
                    if (inter > 0.0f) {
                        float un = __fsub_rn(__fadd_rn(ai2, a0), inter);
                        sup = (__fdiv_rn(inter, un) > NMS_TH);
                    }
                }
                alive &= ~__ballot(sup);
            }
            if (lane < n && ((alive >> lane) & 1ull)) {
                int sidx = (int)ssx2[base + lane];
                atomicOr(&sVWk[sidx >> 6], 1ull << (sidx & 63));
            }
        } else {
            int W4 = (n + 63) >> 6;
            float4 bx4[4]; float ar4[4];
            for (int s = 0; s < W4; ++s) {
                int j = lane + (s << 6);
                if (j < n) { bx4[s] = sbox[base + j]; ar4[s] = sar2[base + j]; }
            }
            ull alive[4];
            for (int s = 0; s < 4; ++s) {
                int remn = n - (s << 6);
                alive[s] = (remn >= 64) ? ~0ull
                         : (remn > 0 ? ((1ull << remn) - 1ull) : 0ull);
            }
            #pragma unroll 1
            for (int i = 0; i < n; ++i) {
                if (!((alive[i >> 6] >> (i & 63)) & 1ull)) continue;
                float4 bi = sbox[base + i];           // uniform LDS read
                float ai2 = sar2[base + i];
                for (int s = 0; s < W4; ++s) {
                    int j = lane + (s << 6);
                    bool sup = false;
                    if (j < n && j > i) {
                        float lt0 = fmaxf(bi.x, bx4[s].x), lt1 = fmaxf(bi.y, bx4[s].y);
                        float rb0 = fminf(bi.z, bx4[s].z), rb1 = fminf(bi.w, bx4[s].w);
                        float w0 = fmaxf(__fsub_rn(rb0, lt0), 0.0f);
                        float w1 = fmaxf(__fsub_rn(rb1, lt1), 0.0f);
                        float inter = __fmul_rn(w0, w1);
                        if (inter > 0.0f) {
                            float un = __fsub_rn(__fadd_rn(ai2, ar4[s]), inter);
                            sup = (__fdiv_rn(inter, un) > NMS_TH);
                        }
                    }
                    alive[s] &= ~__ballot(sup);
                }
            }
            for (int s = 0; s < W4; ++s) {
                int j = lane + (s << 6);
                if (j < n && ((alive[s] >> lane) & 1ull)) {
                    int sidx = (int)ssx2[base + j];
                    atomicOr(&sVWk[sidx >> 6], 1ull << (sidx & 63));
                }
            }
        }
    }
    __syncthreads();

    // ---- top-100 emit (wave 0 only; identical to proven kE) ----
    if (warp == 0) {
        unsigned m = (unsigned)(sVWk[lane >> 1] >> ((lane & 1) << 5));
        int cntk = __popc(m);
        int pre = cntk;
        #pragma unroll
        for (int o = 1; o < 64; o <<= 1) {
            int v = __shfl_up(pre, o);
            if (lane >= o) pre += v;
        }
        int total = __shfl(pre, 63);
        int excl = pre - cntk;

        unsigned mm = m;
        while (mm) {
            int t = __builtin_ctz(mm);
            mm &= mm - 1;
            int rank = excl++;
            if (rank < DETS) {
                int j = lane * 32 + t;
                int g = b * TOPK + j;
                float4 bx = cbox[g];
                *reinterpret_cast<float4*>(out + ((size_t)b * DETS + rank) * 4) = bx;
                out[NIMG * DETS * 4 + b * DETS + rank] = cscore[g];
                out[NIMG * DETS * 5 + b * DETS + rank] = (float)clabel[g];
            }
        }
        int kept100 = (total < DETS) ? total : DETS;
        int F = DETS - kept100;
        if (F > 0) {
            unsigned zm = ~m;
            int zc = __popc(zm);
            int zpre = zc;
            #pragma unroll
            for (int o = 1; o < 64; o <<= 1) {
                int v = __shfl_up(zpre, o);
                if (lane >= o) zpre += v;
            }
            int zexcl = zpre - zc;
            while (zm) {
                int t = __builtin_ctz(zm);
                zm &= zm - 1;
                int zr = zexcl++;
                if (zr < F) {
                    int j = lane * 32 + t;
                    int g = b * TOPK + j;
                    float4 bx = cbox[g];
                    int rank = kept100 + zr;
                    *reinterpret_cast<float4*>(out + ((size_t)b * DETS + rank) * 4) = bx;
                    out[NIMG * DETS * 4 + b * DETS + rank] = -1.0f;
                    out[NIMG * DETS * 5 + b * DETS + rank] = (float)clabel[g];
                }
            }
        }
    }
}

// ---------------- launch ----------------
extern "C" void kernel_launch(void* const* d_in, const int* in_sizes, int n_in,
                              void* d_out, int out_size, void* d_ws, size_t ws_size,
                              hipStream_t stream) {
    const float* logits = (const float*)d_in[0];   // [16000, 91]
    const float* reg    = (const float*)d_in[1];   // [16000, 364]
    const float* props  = (const float*)d_in[2];   // [8, 2000, 4]
    float* out = (float*)d_out;                    // boxes(3200) | scores(800) | labels(800)
    char* ws = (char*)d_ws;

    int* cntv   = (int*)(ws + OFF_CNT);
    ull* vbm2   = (ull*)(ws + OFF_VBM);
    ull* ck     = (ull*)(ws + OFF_CK);
    float4* cbox  = (float4*)(ws + OFF_CBOX);
    float*  cscor = (float*)(ws + OFF_CSCOR);
    int*    clab  = (int*)(ws + OFF_CLAB);

    hipMemsetAsync(ws, 0, 2048, stream);   // zero the padded counters
    hipLaunchKernelGGL(kA, dim3(NROW / 16), dim3(1024), 0, stream,
                       logits, reg, props, ck, cntv, vbm2);
    hipLaunchKernelGGL(kB, dim3(NIMG), dim3(1024), 0, stream,
                       ck, cntv, vbm2, reg, props, cbox, cscor, clab, out);
}

// Round 10
// 140.874 us; speedup vs baseline: 1.1332x; 1.1332x over previous
//
#include <hip/hip_runtime.h>
#include <cstdint>
#include <cstddef>

// ---------------- problem constants ----------------
#define NIMG   8
#define NPROP  2000
#define NCLS   91
#define NFG    90
#define NROW   (NIMG * NPROP)      // 16000
#define TOPK   2048
#define DETS   100
#define CKCAP  32768
#define KREGS  12                  // register-resident keys/thread (12*1024=12288)
#define CLSCAP 512                 // max candidates per (image,class) handled by kN

#define IMG_Wf 1333.0f
#define IMG_Hf 800.0f
#define SCORE_TH 0.05f
#define MINSZ    0.01f
#define NMS_TH   0.5f
#define CLIPV    4.135166556742356f   // log(1000/16) rounded to f32
#define ORD_NEG1 0x407FFFFFu          // ford(-1.0f)
#define PADKEY   (((ull)ORD_NEG1 << 32) | 0xFFFFFFFFull)

typedef unsigned long long ull;

// ---------------- workspace layout (bytes) ----------------
// zeroed region [0, 4096): cntv (8 counters, 256B apart) + keepbm (8*32 ull)
static const size_t OFF_CNT    = 0;                                  // 2048
static const size_t OFF_KBM    = 2048;                               // 8*32*8 = 2048
static const size_t OFF_VBM    = 4096;                               // 16000*2*8
static const size_t OFF_CK     = 262144;                             // 8*32768*8
static const size_t OFF_CBOX   = OFF_CK    + (size_t)NIMG*CKCAP*8;   // 8*2048*16
static const size_t OFF_CSCOR  = OFF_CBOX  + (size_t)NIMG*TOPK*16;   // 8*2048*4
static const size_t OFF_CLAB   = OFF_CSCOR + (size_t)NIMG*TOPK*4;    // 8*2048*4
static const size_t OFF_CLSBOX = OFF_CLAB  + (size_t)NIMG*TOPK*4;    // 8*2048*16
static const size_t OFF_CLSAR  = OFF_CLSBOX+ (size_t)NIMG*TOPK*16;   // 8*2048*4
static const size_t OFF_CLSSX  = OFF_CLSAR + (size_t)NIMG*TOPK*4;    // 8*2048*4
static const size_t OFF_CLSCNT = OFF_CLSSX + (size_t)NIMG*TOPK*4;    // 8*96*4
static const size_t OFF_CLSOFF = OFF_CLSCNT+ (size_t)NIMG*96*4;      // 8*96*4

// ---------------- helpers ----------------
__device__ __forceinline__ unsigned ford(float f) {
    unsigned u = __float_as_uint(f);
    return (u & 0x80000000u) ? ~u : (u | 0x80000000u);
}
__device__ __forceinline__ float fordinv(unsigned x) {
    return (x & 0x80000000u) ? __uint_as_float(x & 0x7FFFFFFFu)
                             : __uint_as_float(~x);
}

// exact op-for-op mirror of reference _decode + clip (no FMA contraction)
__device__ __forceinline__ float4 decode_clip(float4 p, float4 r) {
    float w  = __fsub_rn(p.z, p.x);
    float h  = __fsub_rn(p.w, p.y);
    float cx = __fadd_rn(p.x, __fmul_rn(0.5f, w));
    float cy = __fadd_rn(p.y, __fmul_rn(0.5f, h));
    float dx = __fdiv_rn(r.x, 10.0f);
    float dy = __fdiv_rn(r.y, 10.0f);
    float dw = fminf(__fdiv_rn(r.z, 5.0f), CLIPV);
    float dh = fminf(__fdiv_rn(r.w, 5.0f), CLIPV);
    float pcx = __fadd_rn(__fmul_rn(dx, w), cx);
    float pcy = __fadd_rn(__fmul_rn(dy, h), cy);
    float pw  = __fmul_rn(expf(dw), w);
    float ph  = __fmul_rn(expf(dh), h);
    float x1 = __fsub_rn(pcx, __fmul_rn(0.5f, pw));
    float y1 = __fsub_rn(pcy, __fmul_rn(0.5f, ph));
    float x2 = __fadd_rn(pcx, __fmul_rn(0.5f, pw));
    float y2 = __fadd_rn(pcy, __fmul_rn(0.5f, ph));
    float4 o;
    o.x = fminf(fmaxf(x1, 0.0f), IMG_Wf);
    o.y = fminf(fmaxf(y1, 0.0f), IMG_Hf);
    o.z = fminf(fmaxf(x2, 0.0f), IMG_Wf);
    o.w = fminf(fmaxf(y2, 0.0f), IMG_Hf);
    return o;
}

// bitonic wave-local phase steps (j = jmax..2 via shfl, then j=1 in-thread).
__device__ __forceinline__ void wl_phase(ull& a, ull& b, int l, int base,
                                         int k, int jmax) {
    bool desc = ((base & k) == 0);
    for (int j = jmax; j >= 2; j >>= 1) {
        int pl = l ^ (j >> 1);
        bool lower = ((base & j) == 0);
        ull pa = __shfl(a, pl), pb = __shfl(b, pl);
        bool km = (desc == lower);
        ull na = km ? (a > pa ? a : pa) : (a < pa ? a : pa);
        ull nb = km ? (b > pb ? b : pb) : (b < pb ? b : pb);
        a = na; b = nb;
    }
    ull mx = a > b ? a : b, mn = a > b ? b : a;
    a = desc ? mx : mn; b = desc ? mn : mx;
}

// ============ kernel A: softmax + decode + valid -> compacted keys + row bitmap ============
__global__ __launch_bounds__(1024) void kA(const float* __restrict__ logits,
                                           const float* __restrict__ reg,
                                           const float* __restrict__ props,
                                           ull* __restrict__ ck,
                                           int* __restrict__ cntv,
                                           ull* __restrict__ vbm2) {
    int warp = threadIdx.x >> 6;
    int lane = threadIdx.x & 63;
    int row  = blockIdx.x * 16 + warp;
    int b = row / NPROP;                 // uniform within block
    int n = row - b * NPROP;
    const float* lrow = logits + (size_t)row * NCLS;

    float xa = lrow[lane];
    float xb = (lane < 27) ? lrow[64 + lane] : -INFINITY;
    float mx = fmaxf(xa, xb);
    #pragma unroll
    for (int o = 32; o; o >>= 1) mx = fmaxf(mx, __shfl_xor(mx, o));
    float ea = expf(__fsub_rn(xa, mx));
    float eb = (lane < 27) ? expf(__fsub_rn(xb, mx)) : 0.0f;
    float s  = __fadd_rn(ea, eb);
    #pragma unroll
    for (int o = 32; o; o >>= 1) s = __fadd_rn(s, __shfl_xor(s, o));

    const float4 p = *reinterpret_cast<const float4*>(props + (size_t)row * 4);

    __shared__ int sCnt[32];
    __shared__ int sExc[32];
    __shared__ int sBase;

    ull rowmask[2];
    bool validA[2];
    ull keyA[2];
    #pragma unroll
    for (int it = 0; it < 2; ++it) {
        int c = (it == 0) ? (1 + lane) : (65 + lane);
        bool active = (it == 0) ? true : (lane < 26);
        bool valid = false;
        ull key = 0;
        if (active) {
            float lg = lrow[c];
            float score = __fdiv_rn(expf(__fsub_rn(lg, mx)), s);
            float4 r4 = *reinterpret_cast<const float4*>(
                reg + ((size_t)row * NCLS + c) * 4);
            float4 bx = decode_clip(p, r4);
            float bw = __fsub_rn(bx.z, bx.x);
            float bh = __fsub_rn(bx.w, bx.y);
            valid = (score > SCORE_TH) && (bw >= MINSZ) && (bh >= MINSZ);
            int offidx = n * NFG + (c - 1);
            key = ((ull)ford(score) << 32) |
                  (ull)(0xFFFFFFFFu - (unsigned)offidx);
        }
        ull bal = __ballot(valid);
        rowmask[it] = bal;
        validA[it] = valid;
        keyA[it] = key;
        if (lane == 0) sCnt[warp * 2 + it] = __popcll(bal);
    }
    __syncthreads();
    if (warp == 0) {
        int c = (lane < 32) ? sCnt[lane] : 0;
        int p2 = c;
        #pragma unroll
        for (int o = 1; o < 32; o <<= 1) {
            int v = __shfl_up(p2, o);
            if (lane >= o) p2 += v;
        }
        if (lane == 31) sBase = atomicAdd(&cntv[b * 64], p2);
        if (lane < 32) sExc[lane] = p2 - c;
    }
    __syncthreads();
    int base = sBase;
    #pragma unroll
    for (int it = 0; it < 2; ++it) {
        if (validA[it]) {
            int slot = base + sExc[warp * 2 + it] +
                       __popcll(rowmask[it] & ((1ull << lane) - 1ull));
            if (slot < CKCAP)
                ck[(size_t)b * CKCAP + slot] = keyA[it];
        }
    }
    if (lane == 0) {
        vbm2[(size_t)row * 2]     = rowmask[0];
        vbm2[(size_t)row * 2 + 1] = rowmask[1];
    }
}

// ============ kernel B: per-image exact top-2048 (sorted) + per-class bucketing ============
__global__ __launch_bounds__(1024) void kB(const ull* __restrict__ ck,
                                           const int* __restrict__ cntv,
                                           const ull* __restrict__ vbm2,
                                           const float* __restrict__ reg,
                                           const float* __restrict__ props,
                                           float4* __restrict__ cbox,
                                           float* __restrict__ cscore,
                                           int* __restrict__ clabel,
                                           float4* __restrict__ clsbox,
                                           float* __restrict__ clsarea,
                                           int* __restrict__ clssidx,
                                           int* __restrict__ clscnt,
                                           int* __restrict__ clsoff) {
    int b = blockIdx.x;
    int tid = threadIdx.x;
    int lane = tid & 63, warp = tid >> 6;
    __shared__ ull sk[TOPK];
    __shared__ unsigned histw[16 * 256];    // per-wave histograms (16 KB)
    __shared__ unsigned wtot4[4];
    __shared__ ull sP;
    __shared__ int sRem, sCnt, sDone;
    __shared__ float sMax[16];
    __shared__ float sM1;
    __shared__ int rex[NPROP];
    __shared__ int wsum[16];
    __shared__ ull clsbm[NFG * 33];         // class bitmaps, 33-stride (bank spread)
    __shared__ unsigned wpfx[NFG * 33];     // per-class word-prefix, 33-stride
    __shared__ int ccnt[96], coff[96];

    int cnt = cntv[b * 64];
    if (cnt > CKCAP) cnt = CKCAP;
    const ull* K = ck + (size_t)b * CKCAP;

    if (cnt >= TOPK) {
        // ---- load keys into registers (coalesced, once) ----
        ull kreg[KREGS];
        #pragma unroll
        for (int r = 0; r < KREGS; ++r) {
            int i = tid + (r << 10);
            kreg[r] = (i < cnt) ? K[i] : 0ull;
        }
        // ---- 8x8-bit radix select with short-circuit (keys distinct) ----
        ull P = 0; int rem = TOPK;
        for (int pass = 7; pass >= 0; --pass) {
            int sh = pass * 8;
            *reinterpret_cast<uint4*>(&histw[tid * 4]) = make_uint4(0, 0, 0, 0);
            __syncthreads();
            ull pmask = (pass == 7) ? 0ull : (~0ull << (sh + 8));
            unsigned* hw = &histw[warp << 8];
            #pragma unroll
            for (int r = 0; r < KREGS; ++r) {
                int i = tid + (r << 10);
                if (i < cnt && (kreg[r] & pmask) == P)
                    atomicAdd(&hw[(unsigned)(kreg[r] >> sh) & 255u], 1u);
            }
            for (int i = (KREGS << 10) + tid; i < cnt; i += 1024) {   // rare tail
                ull k2 = K[i];
                if ((k2 & pmask) == P)
                    atomicAdd(&hw[(unsigned)(k2 >> sh) & 255u], 1u);
            }
            __syncthreads();
            unsigned x = 0, pfx = 0;
            if (tid < 256) {
                int d = 255 - tid;
                #pragma unroll
                for (int w = 0; w < 16; ++w) x += histw[(w << 8) + d];
                pfx = x;
                #pragma unroll
                for (int o = 1; o < 64; o <<= 1) {
                    unsigned v = __shfl_up(pfx, o);
                    if (lane >= o) pfx += v;
                }
                if (lane == 63) wtot4[tid >> 6] = pfx;
            }
            __syncthreads();
            if (tid < 256) {
                int d = 255 - tid;
                int ws = tid >> 6;
                unsigned add = 0;
                if (ws > 0) add += wtot4[0];
                if (ws > 1) add += wtot4[1];
                if (ws > 2) add += wtot4[2];
                unsigned pi   = pfx + add;    // suffixIncl(d)
                unsigned excl = pi - x;       // suffixExcl(d)
                if (x && excl < (unsigned)rem && pi >= (unsigned)rem) {
                    sP = P | ((ull)(unsigned)d << sh);
                    int nr = rem - (int)excl;
                    sRem = nr;
                    sDone = ((int)x == nr) ? 1 : 0;   // whole bin selected -> exact
                }
            }
            __syncthreads();
            P = sP; rem = sRem;
            if (sDone) break;      // threshold exact with remaining low bits zero
        }
        if (tid == 0) sCnt = 0;
        __syncthreads();
        // ---- wave-aggregated compaction from registers ----
        #pragma unroll
        for (int r = 0; r < KREGS; ++r) {
            int i = tid + (r << 10);
            bool sel = (i < cnt) && (kreg[r] >= P);
            ull bal = __ballot(sel);
            int cw = __popcll(bal);
            if (cw) {
                int ldr = __ffsll((long long)bal) - 1;
                int bw = 0;
                if (lane == ldr) bw = atomicAdd(&sCnt, cw);
                bw = __shfl(bw, ldr);
                if (sel) {
                    int pos = bw + __popcll(bal & ((1ull << lane) - 1ull));
                    if (pos < TOPK) sk[pos] = kreg[r];
                }
            }
        }
        for (int i = (KREGS << 10) + tid; i < cnt; i += 1024) {       // rare tail
            ull k2 = K[i];
            bool sel = (k2 >= P);
            ull bal = __ballot(sel);
            int cw = __popcll(bal);
            if (cw) {
                int ldr = __ffsll((long long)bal) - 1;
                int bw = 0;
                if (lane == ldr) bw = atomicAdd(&sCnt, cw);
                bw = __shfl(bw, ldr);
                if (sel) {
                    int pos = bw + __popcll(bal & ((1ull << lane) - 1ull));
                    if (pos < TOPK) sk[pos] = k2;
                }
            }
        }
        __syncthreads();
        int fc = sCnt;
        for (int i = fc + tid; i < TOPK; i += 1024) sk[i] = PADKEY;
    } else {
        // take all valid + fill with smallest-index invalid (score -1, ascending idx)
        for (int i = tid; i < cnt; i += 1024) sk[i] = K[i];
        int F = TOPK - cnt;
        const ull* V = vbm2 + (size_t)b * NPROP * 2;
        int r0 = 2 * tid, r1 = r0 + 1;
        int v0 = 0, v1 = 0;
        if (r0 < NPROP) v0 = NFG - __popcll(V[r0 * 2]) - __popcll(V[r0 * 2 + 1]);
        if (r1 < NPROP) v1 = NFG - __popcll(V[r1 * 2]) - __popcll(V[r1 * 2 + 1]);
        int s2 = v0 + v1;
        int pfx = s2;
        #pragma unroll
        for (int o = 1; o < 64; o <<= 1) {
            int t = __shfl_up(pfx, o);
            if (lane >= o) pfx += t;
        }
        if (lane == 63) wsum[warp] = pfx;
        __syncthreads();
        if (tid == 0) {
            int a = 0;
            for (int w = 0; w < 16; ++w) { int t = wsum[w]; wsum[w] = a; a += t; }
        }
        __syncthreads();
        int excl = pfx - s2 + wsum[warp];
        if (r0 < NPROP) rex[r0] = excl;
        if (r1 < NPROP) rex[r1] = excl + v0;
        __syncthreads();
        for (int r = tid; r < NPROP; r += 1024) {
            int e = rex[r];
            if (e < F) {
                ull m0 = V[r * 2], m1 = V[r * 2 + 1];
                int rank = e;
                ull inv = ~m0;
                while (inv && rank < F) {
                    int cb = __builtin_ctzll(inv); inv &= inv - 1;
                    unsigned idx = (unsigned)(r * NFG + cb);
                    sk[cnt + rank] = ((ull)ORD_NEG1 << 32) | (ull)(0xFFFFFFFFu - idx);
                    ++rank;
                }
                inv = (~m1) & ((1ull << 26) - 1ull);
                while (inv && rank < F) {
                    int cb = __builtin_ctzll(inv); inv &= inv - 1;
                    unsigned idx = (unsigned)(r * NFG + 64 + cb);
                    sk[cnt + rank] = ((ull)ORD_NEG1 << 32) | (ull)(0xFFFFFFFFu - idx);
                    ++rank;
                }
            }
        }
    }
    __syncthreads();

    // ---- hybrid bitonic sort, descending (pair-indexed LDS steps) ----
    {
        int ebase = warp * 128 + lane * 2;
        ulonglong2 v = *reinterpret_cast<ulonglong2*>(&sk[ebase]);
        ull a = v.x, bb = v.y;
        #pragma unroll
        for (int k = 2; k <= 128; k <<= 1)
            wl_phase(a, bb, lane, ebase, k, (k >> 1) < 64 ? (k >> 1) : 64);
        v.x = a; v.y = bb;
        *reinterpret_cast<ulonglong2*>(&sk[ebase]) = v;
        for (int k = 256; k <= TOPK; k <<= 1) {
            for (int j = k >> 1; j >= 128; j >>= 1) {
                __syncthreads();
                int i = ((tid & ~(j - 1)) << 1) | (tid & (j - 1));
                int ij = i | j;
                ull x1 = sk[i], x2 = sk[ij];
                bool descSeg = ((i & k) == 0);
                if ((x1 < x2) == descSeg) { sk[i] = x2; sk[ij] = x1; }
            }
            __syncthreads();
            v = *reinterpret_cast<ulonglong2*>(&sk[ebase]);
            a = v.x; bb = v.y;
            wl_phase(a, bb, lane, ebase, k, 64);
            v.x = a; v.y = bb;
            *reinterpret_cast<ulonglong2*>(&sk[ebase]) = v;
        }
    }
    __syncthreads();

    // ---- epilogue: decode candidates, write global arrays ----
    float lmax = 0.0f;
    float4 myb[2]; int myl[2]; float mys[2]; bool vkA[2];
    #pragma unroll
    for (int r = 0; r < 2; ++r) {
        int sidx = tid + r * 1024;
        ull k = sk[sidx];
        unsigned idx = 0xFFFFFFFFu - (unsigned)(k & 0xFFFFFFFFu);
        float score = fordinv((unsigned)(k >> 32));
        int n = (int)(idx / NFG), c = (int)(idx % NFG);     // label = c+1
        int row = b * NPROP + n;
        float4 p  = *reinterpret_cast<const float4*>(props + (size_t)row * 4);
        float4 r4 = *reinterpret_cast<const float4*>(
            reg + ((size_t)row * NCLS + (c + 1)) * 4);
        float4 bx = decode_clip(p, r4);
        myb[r] = bx; myl[r] = c + 1; mys[r] = score;
        vkA[r] = (((unsigned)(k >> 32)) != ORD_NEG1);
        lmax = fmaxf(lmax, fmaxf(fmaxf(bx.x, bx.y), fmaxf(bx.z, bx.w)));
    }
    #pragma unroll
    for (int o = 32; o; o >>= 1) lmax = fmaxf(lmax, __shfl_xor(lmax, o));
    if ((tid & 63) == 0) sMax[tid >> 6] = lmax;
    __syncthreads();
    if (tid == 0) {
        float v = sMax[0];
        for (int i = 1; i < 16; ++i) v = fmaxf(v, sMax[i]);
        sM1 = __fadd_rn(v, 1.0f);            // jnp.max(cand_boxes) + 1.0
    }
    __syncthreads();
    float m1 = sM1;
    float4 obA[2]; float arA[2];
    #pragma unroll
    for (int r = 0; r < 2; ++r) {
        int sidx = tid + r * 1024;
        float off = __fmul_rn((float)myl[r], m1);
        float4 ob;
        ob.x = __fadd_rn(myb[r].x, off);
        ob.y = __fadd_rn(myb[r].y, off);
        ob.z = __fadd_rn(myb[r].z, off);
        ob.w = __fadd_rn(myb[r].w, off);
        float area = __fmul_rn(__fsub_rn(ob.z, ob.x), __fsub_rn(ob.w, ob.y));
        obA[r] = ob; arA[r] = area;
        int g = b * TOPK + sidx;
        cbox[g] = myb[r]; cscore[g] = mys[r]; clabel[g] = myl[r];
    }

    // ---- per-class bucketing (33-stride bitmaps; exact within-class order) ----
    for (int i = tid; i < NFG * 33; i += 1024) clsbm[i] = 0ull;
    __syncthreads();
    #pragma unroll
    for (int r = 0; r < 2; ++r) {
        int sidx = tid + (r << 10);
        if (vkA[r])
            atomicOr(&clsbm[(myl[r] - 1) * 33 + (sidx >> 6)], 1ull << (sidx & 63));
    }
    __syncthreads();
    if (tid < NFG) {
        unsigned run = 0;
        for (int w = 0; w < 32; ++w) {
            wpfx[tid * 33 + w] = run;
            run += (unsigned)__popcll(clsbm[tid * 33 + w]);
        }
        ccnt[tid] = (int)run;
    }
    __syncthreads();
    if (tid == 0) {
        int a = 0;
        for (int c2 = 0; c2 < NFG; ++c2) { coff[c2] = a; a += ccnt[c2]; }
    }
    __syncthreads();
    #pragma unroll
    for (int r = 0; r < 2; ++r) {
        int sidx = tid + (r << 10);
        if (vkA[r]) {
            int cl = myl[r] - 1;
            int rank = (int)wpfx[cl * 33 + (sidx >> 6)] +
                       (int)__popcll(clsbm[cl * 33 + (sidx >> 6)] &
                                     ((1ull << (sidx & 63)) - 1ull));
            int slot = coff[cl] + rank;
            int g2 = b * TOPK + slot;
            clsbox[g2] = obA[r]; clsarea[g2] = arA[r]; clssidx[g2] = sidx;
        }
    }
    if (tid < NFG) {
        clscnt[b * 96 + tid] = ccnt[tid];
        clsoff[b * 96 + tid] = coff[tid];
    }
}

// ============ kernel N: per-(image,class) greedy NMS (1 wave each) ============
__global__ __launch_bounds__(64) void kN(const float4* __restrict__ clsbox,
                                         const float* __restrict__ clsarea,
                                         const int* __restrict__ clssidx,
                                         const int* __restrict__ clscnt,
                                         const int* __restrict__ clsoff,
                                         ull* __restrict__ keepbm) {
    int bc = blockIdx.x;
    int b = bc / NFG, c = bc - b * NFG;
    int n = clscnt[b * 96 + c];
    if (n <= 0) return;
    if (n > CLSCAP) n = CLSCAP;   // unreachable at observed densities
    int lane = threadIdx.x;
    int W = (n + 63) >> 6;
    __shared__ float4 sbox[CLSCAP];
    __shared__ float  sar[CLSCAP];
    __shared__ int    ssx[CLSCAP];
    __shared__ ull    smask[CLSCAP * 8];
    int base = b * TOPK + clsoff[b * 96 + c];
    for (int t = lane; t < n; t += 64) {
        sbox[t] = clsbox[base + t];
        sar[t]  = clsarea[base + t];
        ssx[t]  = clssidx[base + t];
    }
    __syncthreads();
    for (int i = lane; i < n; i += 64) {
        float4 a = sbox[i]; float ai = sar[i];
        for (int w = 0; w < W; ++w) {
            ull word = 0;
            int jn = n - (w << 6); if (jn > 64) jn = 64;
            for (int s = 0; s < jn; ++s) {
                int j = (w << 6) + s;
                if (j > i) {
                    float4 cc = sbox[j];
                    float lt0 = fmaxf(a.x, cc.x), lt1 = fmaxf(a.y, cc.y);
                    float rb0 = fminf(a.z, cc.z), rb1 = fminf(a.w, cc.w);
                    float w0 = fmaxf(__fsub_rn(rb0, lt0), 0.0f);
                    float w1 = fmaxf(__fsub_rn(rb1, lt1), 0.0f);
                    float inter = __fmul_rn(w0, w1);
                    if (inter > 0.0f) {
                        float un = __fsub_rn(__fadd_rn(ai, sar[j]), inter);
                        if (__fdiv_rn(inter, un) > NMS_TH) word |= (1ull << s);
                    }
                }
            }
            smask[i * W + w] = word;
        }
    }
    __syncthreads();
    ull alive = 0;
    if (lane < W) {
        int rem = n - (lane << 6);
        alive = (rem >= 64) ? ~0ull : ((1ull << rem) - 1ull);
    }
    for (int i = 0; i < n; ++i) {
        ull aw = __shfl(alive, i >> 6);
        if ((aw >> (i & 63)) & 1ull) {
            if (lane < W) alive &= ~smask[i * W + lane];
        }
    }
    if (lane < W) {
        ull bits = alive;
        while (bits) {
            int s = __builtin_ctzll(bits); bits &= bits - 1;
            int sidx = ssx[(lane << 6) + s];
            atomicOr(&keepbm[b * 32 + (sidx >> 6)], 1ull << (sidx & 63));
        }
    }
}

// ============ kernel E: top-100 emit from keep bitmap ============
__global__ __launch_bounds__(64) void kE(const ull* __restrict__ keepbm,
                                         const float4* __restrict__ cbox,
                                         const float* __restrict__ cscore,
                                         const int* __restrict__ clabel,
                                         float* __restrict__ out) {
    int b = blockIdx.x;
    int lane = threadIdx.x;
    __shared__ ull sKeep[32];
    if (lane < 32) sKeep[lane] = keepbm[b * 32 + lane];
    __syncthreads();

    // lane owns candidates j in [lane*32, lane*32+32)
    unsigned m = (unsigned)(sKeep[lane >> 1] >> ((lane & 1) << 5));

    int cntk = __popc(m);
    int pre = cntk;
    #pragma unroll
    for (int o = 1; o < 64; o <<= 1) {
        int v = __shfl_up(pre, o);
        if (lane >= o) pre += v;
    }
    int total = __shfl(pre, 63);
    int excl = pre - cntk;

    unsigned mm = m;
    while (mm) {
        int t = __builtin_ctz(mm);
        mm &= mm - 1;
        int rank = excl++;
        if (rank < DETS) {
            int j = lane * 32 + t;
            int g = b * TOPK + j;
            float4 bx = cbox[g];
            *reinterpret_cast<float4*>(out + ((size_t)b * DETS + rank) * 4) = bx;
            out[NIMG * DETS * 4 + b * DETS + rank] = cscore[g];
            out[NIMG * DETS * 5 + b * DETS + rank] = (float)clabel[g];
        }
    }
    int kept100 = (total < DETS) ? total : DETS;
    int F = DETS - kept100;
    if (F > 0) {
        unsigned zm = ~m;
        int zc = __popc(zm);
        int zpre = zc;
        #pragma unroll
        for (int o = 1; o < 64; o <<= 1) {
            int v = __shfl_up(zpre, o);
            if (lane >= o) zpre += v;
        }
        int zexcl = zpre - zc;
        while (zm) {
            int t = __builtin_ctz(zm);
            zm &= zm - 1;
            int zr = zexcl++;
            if (zr < F) {
                int j = lane * 32 + t;
                int g = b * TOPK + j;
                float4 bx = cbox[g];
                int rank = kept100 + zr;
                *reinterpret_cast<float4*>(out + ((size_t)b * DETS + rank) * 4) = bx;
                out[NIMG * DETS * 4 + b * DETS + rank] = -1.0f;
                out[NIMG * DETS * 5 + b * DETS + rank] = (float)clabel[g];
            }
        }
    }
}

// ---------------- launch ----------------
extern "C" void kernel_launch(void* const* d_in, const int* in_sizes, int n_in,
                              void* d_out, int out_size, void* d_ws, size_t ws_size,
                              hipStream_t stream) {
    const float* logits = (const float*)d_in[0];   // [16000, 91]
    const float* reg    = (const float*)d_in[1];   // [16000, 364]
    const float* props  = (const float*)d_in[2];   // [8, 2000, 4]
    float* out = (float*)d_out;                    // boxes(3200) | scores(800) | labels(800)
    char* ws = (char*)d_ws;

    int* cntv   = (int*)(ws + OFF_CNT);
    ull* keepbm = (ull*)(ws + OFF_KBM);
    ull* vbm2   = (ull*)(ws + OFF_VBM);
    ull* ck     = (ull*)(ws + OFF_CK);
    float4* cbox   = (float4*)(ws + OFF_CBOX);
    float*  cscor  = (float*)(ws + OFF_CSCOR);
    int*    clab   = (int*)(ws + OFF_CLAB);
    float4* clsbox = (float4*)(ws + OFF_CLSBOX);
    float*  clsar  = (float*)(ws + OFF_CLSAR);
    int*    clssx  = (int*)(ws + OFF_CLSSX);
    int*    clscnt = (int*)(ws + OFF_CLSCNT);
    int*    clsoff = (int*)(ws + OFF_CLSOFF);

    hipMemsetAsync(ws, 0, 4096, stream);   // zero counters + keep bitmap
    hipLaunchKernelGGL(kA, dim3(NROW / 16), dim3(1024), 0, stream,
                       logits, reg, props, ck, cntv, vbm2);
    hipLaunchKernelGGL(kB, dim3(NIMG), dim3(1024), 0, stream,
                       ck, cntv, vbm2, reg, props, cbox, cscor, clab,
                       clsbox, clsar, clssx, clscnt, clsoff);
    hipLaunchKernelGGL(kN, dim3(NIMG * NFG), dim3(64), 0, stream,
                       clsbox, clsar, clssx, clscnt, clsoff, keepbm);
    hipLaunchKernelGGL(kE, dim3(NIMG), dim3(64), 0, stream,
                       keepbm, cbox, cscor, clab, out);
}

// Round 11
// 139.787 us; speedup vs baseline: 1.1421x; 1.0078x over previous
//
#include <hip/hip_runtime.h>
#include <cstdint>
#include <cstddef>

// ---------------- problem constants ----------------
#define NIMG   8
#define NPROP  2000
#define NCLS   91
#define NFG    90
#define NROW   (NIMG * NPROP)      // 16000
#define TOPK   2048
#define DETS   100
#define CKCAP  32768
#define KREGS  12                  // register-resident keys/thread (12*1024=12288)
#define CLSCAP 512                 // max candidates per (image,class) handled by kN

#define IMG_Wf 1333.0f
#define IMG_Hf 800.0f
#define SCORE_TH 0.05f
#define MINSZ    0.01f
#define NMS_TH   0.5f
#define CLIPV    4.135166556742356f   // log(1000/16) rounded to f32
#define ORD_NEG1 0x407FFFFFu          // ford(-1.0f)
#define PADKEY   (((ull)ORD_NEG1 << 32) | 0xFFFFFFFFull)

typedef unsigned long long ull;

// ---------------- workspace layout (bytes) ----------------
// zeroed region [0, 2048): cntv (8 counters, 256B apart)
static const size_t OFF_CNT    = 0;                                  // 2048
static const size_t OFF_VBM    = 4096;                               // 16000*2*8
static const size_t OFF_CK     = 262144;                             // 8*32768*8
static const size_t OFF_CBOX   = OFF_CK    + (size_t)NIMG*CKCAP*8;   // 8*2048*16
static const size_t OFF_CSCOR  = OFF_CBOX  + (size_t)NIMG*TOPK*16;   // 8*2048*4
static const size_t OFF_CLAB   = OFF_CSCOR + (size_t)NIMG*TOPK*4;    // 8*2048*4
static const size_t OFF_CLSBOX = OFF_CLAB  + (size_t)NIMG*TOPK*4;    // 8*2048*16
static const size_t OFF_CLSAR  = OFF_CLSBOX+ (size_t)NIMG*TOPK*16;   // 8*2048*4
static const size_t OFF_CLSSX  = OFF_CLSAR + (size_t)NIMG*TOPK*4;    // 8*2048*4
static const size_t OFF_CLSCNT = OFF_CLSSX + (size_t)NIMG*TOPK*4;    // 8*96*4
static const size_t OFF_CLSOFF = OFF_CLSCNT+ (size_t)NIMG*96*4;      // 8*96*4
static const size_t OFF_KCLS   = OFF_CLSOFF+ (size_t)NIMG*96*4;      // 8*96*8 ull = 49KB

// ---------------- helpers ----------------
__device__ __forceinline__ unsigned ford(float f) {
    unsigned u = __float_as_uint(f);
    return (u & 0x80000000u) ? ~u : (u | 0x80000000u);
}
__device__ __forceinline__ float fordinv(unsigned x) {
    return (x & 0x80000000u) ? __uint_as_float(x & 0x7FFFFFFFu)
                             : __uint_as_float(~x);
}

// exact op-for-op mirror of reference _decode + clip (no FMA contraction)
__device__ __forceinline__ float4 decode_clip(float4 p, float4 r) {
    float w  = __fsub_rn(p.z, p.x);
    float h  = __fsub_rn(p.w, p.y);
    float cx = __fadd_rn(p.x, __fmul_rn(0.5f, w));
    float cy = __fadd_rn(p.y, __fmul_rn(0.5f, h));
    float dx = __fdiv_rn(r.x, 10.0f);
    float dy = __fdiv_rn(r.y, 10.0f);
    float dw = fminf(__fdiv_rn(r.z, 5.0f), CLIPV);
    float dh = fminf(__fdiv_rn(r.w, 5.0f), CLIPV);
    float pcx = __fadd_rn(__fmul_rn(dx, w), cx);
    float pcy = __fadd_rn(__fmul_rn(dy, h), cy);
    float pw  = __fmul_rn(expf(dw), w);
    float ph  = __fmul_rn(expf(dh), h);
    float x1 = __fsub_rn(pcx, __fmul_rn(0.5f, pw));
    float y1 = __fsub_rn(pcy, __fmul_rn(0.5f, ph));
    float x2 = __fadd_rn(pcx, __fmul_rn(0.5f, pw));
    float y2 = __fadd_rn(pcy, __fmul_rn(0.5f, ph));
    float4 o;
    o.x = fminf(fmaxf(x1, 0.0f), IMG_Wf);
    o.y = fminf(fmaxf(y1, 0.0f), IMG_Hf);
    o.z = fminf(fmaxf(x2, 0.0f), IMG_Wf);
    o.w = fminf(fmaxf(y2, 0.0f), IMG_Hf);
    return o;
}

// bitonic wave-local phase steps (j = jmax..2 via shfl, then j=1 in-thread).
__device__ __forceinline__ void wl_phase(ull& a, ull& b, int l, int base,
                                         int k, int jmax) {
    bool desc = ((base & k) == 0);
    for (int j = jmax; j >= 2; j >>= 1) {
        int pl = l ^ (j >> 1);
        bool lower = ((base & j) == 0);
        ull pa = __shfl(a, pl), pb = __shfl(b, pl);
        bool km = (desc == lower);
        ull na = km ? (a > pa ? a : pa) : (a < pa ? a : pa);
        ull nb = km ? (b > pb ? b : pb) : (b < pb ? b : pb);
        a = na; b = nb;
    }
    ull mx = a > b ? a : b, mn = a > b ? b : a;
    a = desc ? mx : mn; b = desc ? mn : mx;
}

// ============ kernel A: softmax + decode + valid -> compacted keys + row bitmap ============
__global__ __launch_bounds__(1024) void kA(const float* __restrict__ logits,
                                           const float* __restrict__ reg,
                                           const float* __restrict__ props,
                                           ull* __restrict__ ck,
                                           int* __restrict__ cntv,
                                           ull* __restrict__ vbm2) {
    int warp = threadIdx.x >> 6;
    int lane = threadIdx.x & 63;
    int row  = blockIdx.x * 16 + warp;
    int b = row / NPROP;                 // uniform within block
    int n = row - b * NPROP;
    const float* lrow = logits + (size_t)row * NCLS;

    float xa = lrow[lane];
    float xb = (lane < 27) ? lrow[64 + lane] : -INFINITY;
    float mx = fmaxf(xa, xb);
    #pragma unroll
    for (int o = 32; o; o >>= 1) mx = fmaxf(mx, __shfl_xor(mx, o));
    float ea = expf(__fsub_rn(xa, mx));
    float eb = (lane < 27) ? expf(__fsub_rn(xb, mx)) : 0.0f;
    float s  = __fadd_rn(ea, eb);
    #pragma unroll
    for (int o = 32; o; o >>= 1) s = __fadd_rn(s, __shfl_xor(s, o));

    const float4 p = *reinterpret_cast<const float4*>(props + (size_t)row * 4);

    __shared__ int sCnt[32];
    __shared__ int sExc[32];
    __shared__ int sBase;

    ull rowmask[2];
    bool validA[2];
    ull keyA[2];
    #pragma unroll
    for (int it = 0; it < 2; ++it) {
        int c = (it == 0) ? (1 + lane) : (65 + lane);
        bool active = (it == 0) ? true : (lane < 26);
        bool valid = false;
        ull key = 0;
        if (active) {
            float lg = lrow[c];
            float score = __fdiv_rn(expf(__fsub_rn(lg, mx)), s);
            float4 r4 = *reinterpret_cast<const float4*>(
                reg + ((size_t)row * NCLS + c) * 4);
            float4 bx = decode_clip(p, r4);
            float bw = __fsub_rn(bx.z, bx.x);
            float bh = __fsub_rn(bx.w, bx.y);
            valid = (score > SCORE_TH) && (bw >= MINSZ) && (bh >= MINSZ);
            int offidx = n * NFG + (c - 1);
            key = ((ull)ford(score) << 32) |
                  (ull)(0xFFFFFFFFu - (unsigned)offidx);
        }
        ull bal = __ballot(valid);
        rowmask[it] = bal;
        validA[it] = valid;
        keyA[it] = key;
        if (lane == 0) sCnt[warp * 2 + it] = __popcll(bal);
    }
    __syncthreads();
    if (warp == 0) {
        int c = (lane < 32) ? sCnt[lane] : 0;
        int p2 = c;
        #pragma unroll
        for (int o = 1; o < 32; o <<= 1) {
            int v = __shfl_up(p2, o);
            if (lane >= o) p2 += v;
        }
        if (lane == 31) sBase = atomicAdd(&cntv[b * 64], p2);
        if (lane < 32) sExc[lane] = p2 - c;
    }
    __syncthreads();
    int base = sBase;
    #pragma unroll
    for (int it = 0; it < 2; ++it) {
        if (validA[it]) {
            int slot = base + sExc[warp * 2 + it] +
                       __popcll(rowmask[it] & ((1ull << lane) - 1ull));
            if (slot < CKCAP)
                ck[(size_t)b * CKCAP + slot] = keyA[it];
        }
    }
    if (lane == 0) {
        vbm2[(size_t)row * 2]     = rowmask[0];
        vbm2[(size_t)row * 2 + 1] = rowmask[1];
    }
}

// ============ kernel B: per-image exact top-2048 (sorted) + per-class bucketing ============
__global__ __launch_bounds__(1024) void kB(const ull* __restrict__ ck,
                                           const int* __restrict__ cntv,
                                           const ull* __restrict__ vbm2,
                                           const float* __restrict__ reg,
                                           const float* __restrict__ props,
                                           float4* __restrict__ cbox,
                                           float* __restrict__ cscore,
                                           int* __restrict__ clabel,
                                           float4* __restrict__ clsbox,
                                           float* __restrict__ clsarea,
                                           int* __restrict__ clssidx,
                                           int* __restrict__ clscnt,
                                           int* __restrict__ clsoff) {
    int b = blockIdx.x;
    int tid = threadIdx.x;
    int lane = tid & 63, warp = tid >> 6;
    __shared__ ull sk[TOPK];
    __shared__ unsigned histw[16 * 256];    // per-wave histograms (16 KB)
    __shared__ unsigned wtot4[4];
    __shared__ ull sP;
    __shared__ int sRem, sCnt, sDone;
    __shared__ float sMax[16];
    __shared__ float sM1;
    __shared__ int rex[NPROP];
    __shared__ int wsum[16];
    __shared__ ull clsbm[NFG * 33];         // class bitmaps, 33-stride (bank spread)
    __shared__ unsigned wpfx[NFG * 33];     // per-class word-prefix, 33-stride
    __shared__ int ccnt[96], coff[96];

    int cnt = cntv[b * 64];
    if (cnt > CKCAP) cnt = CKCAP;
    const ull* K = ck + (size_t)b * CKCAP;

    if (cnt >= TOPK) {
        // ---- load keys into registers (coalesced, once) ----
        ull kreg[KREGS];
        #pragma unroll
        for (int r = 0; r < KREGS; ++r) {
            int i = tid + (r << 10);
            kreg[r] = (i < cnt) ? K[i] : 0ull;
        }
        // ---- 8x8-bit radix select with short-circuit (keys distinct) ----
        ull P = 0; int rem = TOPK;
        for (int pass = 7; pass >= 0; --pass) {
            int sh = pass * 8;
            *reinterpret_cast<uint4*>(&histw[tid * 4]) = make_uint4(0, 0, 0, 0);
            __syncthreads();
            ull pmask = (pass == 7) ? 0ull : (~0ull << (sh + 8));
            unsigned* hw = &histw[warp << 8];
            #pragma unroll
            for (int r = 0; r < KREGS; ++r) {
                int i = tid + (r << 10);
                if (i < cnt && (kreg[r] & pmask) == P)
                    atomicAdd(&hw[(unsigned)(kreg[r] >> sh) & 255u], 1u);
            }
            for (int i = (KREGS << 10) + tid; i < cnt; i += 1024) {   // rare tail
                ull k2 = K[i];
                if ((k2 & pmask) == P)
                    atomicAdd(&hw[(unsigned)(k2 >> sh) & 255u], 1u);
            }
            __syncthreads();
            unsigned x = 0, pfx = 0;
            if (tid < 256) {
                int d = 255 - tid;
                #pragma unroll
                for (int w = 0; w < 16; ++w) x += histw[(w << 8) + d];
                pfx = x;
                #pragma unroll
                for (int o = 1; o < 64; o <<= 1) {
                    unsigned v = __shfl_up(pfx, o);
                    if (lane >= o) pfx += v;
                }
                if (lane == 63) wtot4[tid >> 6] = pfx;
            }
            __syncthreads();
            if (tid < 256) {
                int d = 255 - tid;
                int ws = tid >> 6;
                unsigned add = 0;
                if (ws > 0) add += wtot4[0];
                if (ws > 1) add += wtot4[1];
                if (ws > 2) add += wtot4[2];
                unsigned pi   = pfx + add;    // suffixIncl(d)
                unsigned excl = pi - x;       // suffixExcl(d)
                if (x && excl < (unsigned)rem && pi >= (unsigned)rem) {
                    sP = P | ((ull)(unsigned)d << sh);
                    int nr = rem - (int)excl;
                    sRem = nr;
                    sDone = ((int)x == nr) ? 1 : 0;   // whole bin selected -> exact
                }
            }
            __syncthreads();
            P = sP; rem = sRem;
            if (sDone) break;      // threshold exact with remaining low bits zero
        }
        if (tid == 0) sCnt = 0;
        __syncthreads();
        // ---- wave-aggregated compaction from registers ----
        #pragma unroll
        for (int r = 0; r < KREGS; ++r) {
            int i = tid + (r << 10);
            bool sel = (i < cnt) && (kreg[r] >= P);
            ull bal = __ballot(sel);
            int cw = __popcll(bal);
            if (cw) {
                int ldr = __ffsll((long long)bal) - 1;
                int bw = 0;
                if (lane == ldr) bw = atomicAdd(&sCnt, cw);
                bw = __shfl(bw, ldr);
                if (sel) {
                    int pos = bw + __popcll(bal & ((1ull << lane) - 1ull));
                    if (pos < TOPK) sk[pos] = kreg[r];
                }
            }
        }
        for (int i = (KREGS << 10) + tid; i < cnt; i += 1024) {       // rare tail
            ull k2 = K[i];
            bool sel = (k2 >= P);
            ull bal = __ballot(sel);
            int cw = __popcll(bal);
            if (cw) {
                int ldr = __ffsll((long long)bal) - 1;
                int bw = 0;
                if (lane == ldr) bw = atomicAdd(&sCnt, cw);
                bw = __shfl(bw, ldr);
                if (sel) {
                    int pos = bw + __popcll(bal & ((1ull << lane) - 1ull));
                    if (pos < TOPK) sk[pos] = k2;
                }
            }
        }
        __syncthreads();
        int fc = sCnt;
        for (int i = fc + tid; i < TOPK; i += 1024) sk[i] = PADKEY;
    } else {
        // take all valid + fill with smallest-index invalid (score -1, ascending idx)
        for (int i = tid; i < cnt; i += 1024) sk[i] = K[i];
        int F = TOPK - cnt;
        const ull* V = vbm2 + (size_t)b * NPROP * 2;
        int r0 = 2 * tid, r1 = r0 + 1;
        int v0 = 0, v1 = 0;
        if (r0 < NPROP) v0 = NFG - __popcll(V[r0 * 2]) - __popcll(V[r0 * 2 + 1]);
        if (r1 < NPROP) v1 = NFG - __popcll(V[r1 * 2]) - __popcll(V[r1 * 2 + 1]);
        int s2 = v0 + v1;
        int pfx = s2;
        #pragma unroll
        for (int o = 1; o < 64; o <<= 1) {
            int t = __shfl_up(pfx, o);
            if (lane >= o) pfx += t;
        }
        if (lane == 63) wsum[warp] = pfx;
        __syncthreads();
        if (tid == 0) {
            int a = 0;
            for (int w = 0; w < 16; ++w) { int t = wsum[w]; wsum[w] = a; a += t; }
        }
        __syncthreads();
        int excl = pfx - s2 + wsum[warp];
        if (r0 < NPROP) rex[r0] = excl;
        if (r1 < NPROP) rex[r1] = excl + v0;
        __syncthreads();
        for (int r = tid; r < NPROP; r += 1024) {
            int e = rex[r];
            if (e < F) {
                ull m0 = V[r * 2], m1 = V[r * 2 + 1];
                int rank = e;
                ull inv = ~m0;
                while (inv && rank < F) {
                    int cb = __builtin_ctzll(inv); inv &= inv - 1;
                    unsigned idx = (unsigned)(r * NFG + cb);
                    sk[cnt + rank] = ((ull)ORD_NEG1 << 32) | (ull)(0xFFFFFFFFu - idx);
                    ++rank;
                }
                inv = (~m1) & ((1ull << 26) - 1ull);
                while (inv && rank < F) {
                    int cb = __builtin_ctzll(inv); inv &= inv - 1;
                    unsigned idx = (unsigned)(r * NFG + 64 + cb);
                    sk[cnt + rank] = ((ull)ORD_NEG1 << 32) | (ull)(0xFFFFFFFFu - idx);
                    ++rank;
                }
            }
        }
    }
    __syncthreads();

    // ---- hybrid bitonic sort, descending (pair-indexed LDS steps) ----
    {
        int ebase = warp * 128 + lane * 2;
        ulonglong2 v = *reinterpret_cast<ulonglong2*>(&sk[ebase]);
        ull a = v.x, bb = v.y;
        #pragma unroll
        for (int k = 2; k <= 128; k <<= 1)
            wl_phase(a, bb, lane, ebase, k, (k >> 1) < 64 ? (k >> 1) : 64);
        v.x = a; v.y = bb;
        *reinterpret_cast<ulonglong2*>(&sk[ebase]) = v;
        for (int k = 256; k <= TOPK; k <<= 1) {
            for (int j = k >> 1; j >= 128; j >>= 1) {
                __syncthreads();
                int i = ((tid & ~(j - 1)) << 1) | (tid & (j - 1));
                int ij = i | j;
                ull x1 = sk[i], x2 = sk[ij];
                bool descSeg = ((i & k) == 0);
                if ((x1 < x2) == descSeg) { sk[i] = x2; sk[ij] = x1; }
            }
            __syncthreads();
            v = *reinterpret_cast<ulonglong2*>(&sk[ebase]);
            a = v.x; bb = v.y;
            wl_phase(a, bb, lane, ebase, k, 64);
            v.x = a; v.y = bb;
            *reinterpret_cast<ulonglong2*>(&sk[ebase]) = v;
        }
    }
    __syncthreads();

    // ---- epilogue: decode candidates, write global arrays ----
    float lmax = 0.0f;
    float4 myb[2]; int myl[2]; float mys[2]; bool vkA[2];
    #pragma unroll
    for (int r = 0; r < 2; ++r) {
        int sidx = tid + r * 1024;
        ull k = sk[sidx];
        unsigned idx = 0xFFFFFFFFu - (unsigned)(k & 0xFFFFFFFFu);
        float score = fordinv((unsigned)(k >> 32));
        int n = (int)(idx / NFG), c = (int)(idx % NFG);     // label = c+1
        int row = b * NPROP + n;
        float4 p  = *reinterpret_cast<const float4*>(props + (size_t)row * 4);
        float4 r4 = *reinterpret_cast<const float4*>(
            reg + ((size_t)row * NCLS + (c + 1)) * 4);
        float4 bx = decode_clip(p, r4);
        myb[r] = bx; myl[r] = c + 1; mys[r] = score;
        vkA[r] = (((unsigned)(k >> 32)) != ORD_NEG1);
        lmax = fmaxf(lmax, fmaxf(fmaxf(bx.x, bx.y), fmaxf(bx.z, bx.w)));
    }
    #pragma unroll
    for (int o = 32; o; o >>= 1) lmax = fmaxf(lmax, __shfl_xor(lmax, o));
    if ((tid & 63) == 0) sMax[tid >> 6] = lmax;
    __syncthreads();
    if (tid == 0) {
        float v = sMax[0];
        for (int i = 1; i < 16; ++i) v = fmaxf(v, sMax[i]);
        sM1 = __fadd_rn(v, 1.0f);            // jnp.max(cand_boxes) + 1.0
    }
    __syncthreads();
    float m1 = sM1;
    float4 obA[2]; float arA[2];
    #pragma unroll
    for (int r = 0; r < 2; ++r) {
        int sidx = tid + r * 1024;
        float off = __fmul_rn((float)myl[r], m1);
        float4 ob;
        ob.x = __fadd_rn(myb[r].x, off);
        ob.y = __fadd_rn(myb[r].y, off);
        ob.z = __fadd_rn(myb[r].z, off);
        ob.w = __fadd_rn(myb[r].w, off);
        float area = __fmul_rn(__fsub_rn(ob.z, ob.x), __fsub_rn(ob.w, ob.y));
        obA[r] = ob; arA[r] = area;
        int g = b * TOPK + sidx;
        cbox[g] = myb[r]; cscore[g] = mys[r]; clabel[g] = myl[r];
    }

    // ---- per-class bucketing (33-stride bitmaps; exact within-class order) ----
    for (int i = tid; i < NFG * 33; i += 1024) clsbm[i] = 0ull;
    __syncthreads();
    #pragma unroll
    for (int r = 0; r < 2; ++r) {
        int sidx = tid + (r << 10);
        if (vkA[r])
            atomicOr(&clsbm[(myl[r] - 1) * 33 + (sidx >> 6)], 1ull << (sidx & 63));
    }
    __syncthreads();
    if (tid < NFG) {
        unsigned run = 0;
        for (int w = 0; w < 32; ++w) {
            wpfx[tid * 33 + w] = run;
            run += (unsigned)__popcll(clsbm[tid * 33 + w]);
        }
        ccnt[tid] = (int)run;
    }
    __syncthreads();
    if (tid == 0) {
        int a = 0;
        for (int c2 = 0; c2 < NFG; ++c2) { coff[c2] = a; a += ccnt[c2]; }
    }
    __syncthreads();
    #pragma unroll
    for (int r = 0; r < 2; ++r) {
        int sidx = tid + (r << 10);
        if (vkA[r]) {
            int cl = myl[r] - 1;
            int rank = (int)wpfx[cl * 33 + (sidx >> 6)] +
                       (int)__popcll(clsbm[cl * 33 + (sidx >> 6)] &
                                     ((1ull << (sidx & 63)) - 1ull));
            int slot = coff[cl] + rank;
            int g2 = b * TOPK + slot;
            clsbox[g2] = obA[r]; clsarea[g2] = arA[r]; clssidx[g2] = sidx;
        }
    }
    if (tid < NFG) {
        clscnt[b * 96 + tid] = ccnt[tid];
        clsoff[b * 96 + tid] = coff[tid];
    }
}

// ============ kernel N: per-(image,class) greedy NMS -> per-class alive words ============
// No global atomics: alive mask stored as plain stores into keepcls[(b*96+c)*8 + w].
__global__ __launch_bounds__(64) void kN(const float4* __restrict__ clsbox,
                                         const float* __restrict__ clsarea,
                                         const int* __restrict__ clscnt,
                                         const int* __restrict__ clsoff,
                                         ull* __restrict__ keepcls) {
    int bc = blockIdx.x;
    int b = bc / NFG, c = bc - b * NFG;
    int n = clscnt[b * 96 + c];
    if (n <= 0) return;
    if (n > CLSCAP) n = CLSCAP;   // unreachable at observed densities
    int lane = threadIdx.x;
    int base = b * TOPK + clsoff[b * 96 + c];

    if (n <= 64) {
        // ballot fast path (R9-verified logic, op-identical IoU)
        float4 b0; float a0 = 0.0f;
        if (lane < n) {
            b0 = clsbox[base + lane];
            a0 = clsarea[base + lane];
        }
        ull alive = (n == 64) ? ~0ull : ((1ull << n) - 1ull);
        #pragma unroll 1
        for (int i = 0; i < n; ++i) {
            if (!((alive >> i) & 1ull)) continue;
            float bix = __shfl(b0.x, i), biy = __shfl(b0.y, i);
            float biz = __shfl(b0.z, i), biw = __shfl(b0.w, i);
            float ai2 = __shfl(a0, i);
            bool sup = false;
            if (lane < n && lane > i) {
                float lt0 = fmaxf(bix, b0.x), lt1 = fmaxf(biy, b0.y);
                float rb0 = fminf(biz, b0.z), rb1 = fminf(biw, b0.w);
                float w0 = fmaxf(__fsub_rn(rb0, lt0), 0.0f);
                float w1 = fmaxf(__fsub_rn(rb1, lt1), 0.0f);
                float inter = __fmul_rn(w0, w1);
                if (inter > 0.0f) {
                    float un = __fsub_rn(__fadd_rn(ai2, a0), inter);
                    sup = (__fdiv_rn(inter, un) > NMS_TH);
                }
            }
            alive &= ~__ballot(sup);
        }
        if (lane == 0) keepcls[(size_t)(b * 96 + c) * 8] = alive;
        return;
    }

    // general path (R8-verified smask structure)
    int W = (n + 63) >> 6;
    __shared__ float4 sbox[CLSCAP];
    __shared__ float  sar[CLSCAP];
    __shared__ ull    smask[CLSCAP * 8];
    for (int t = lane; t < n; t += 64) {
        sbox[t] = clsbox[base + t];
        sar[t]  = clsarea[base + t];
    }
    __syncthreads();
    for (int i = lane; i < n; i += 64) {
        float4 a = sbox[i]; float ai = sar[i];
        for (int w = 0; w < W; ++w) {
            ull word = 0;
            int jn = n - (w << 6); if (jn > 64) jn = 64;
            for (int s = 0; s < jn; ++s) {
                int j = (w << 6) + s;
                if (j > i) {
                    float4 cc = sbox[j];
                    float lt0 = fmaxf(a.x, cc.x), lt1 = fmaxf(a.y, cc.y);
                    float rb0 = fminf(a.z, cc.z), rb1 = fminf(a.w, cc.w);
                    float w0 = fmaxf(__fsub_rn(rb0, lt0), 0.0f);
                    float w1 = fmaxf(__fsub_rn(rb1, lt1), 0.0f);
                    float inter = __fmul_rn(w0, w1);
                    if (inter > 0.0f) {
                        float un = __fsub_rn(__fadd_rn(ai, sar[j]), inter);
                        if (__fdiv_rn(inter, un) > NMS_TH) word |= (1ull << s);
                    }
                }
            }
            smask[i * W + w] = word;
        }
    }
    __syncthreads();
    ull alive = 0;
    if (lane < W) {
        int rem = n - (lane << 6);
        alive = (rem >= 64) ? ~0ull : ((1ull << rem) - 1ull);
    }
    for (int i = 0; i < n; ++i) {
        ull aw = __shfl(alive, i >> 6);
        if ((aw >> (i & 63)) & 1ull) {
            if (lane < W) alive &= ~smask[i * W + lane];
        }
    }
    if (lane < W) keepcls[(size_t)(b * 96 + c) * 8 + lane] = alive;
}

// ============ kernel E: rebuild keep bitmap in LDS + top-100 emit ============
__global__ __launch_bounds__(64) void kE(const ull* __restrict__ keepcls,
                                         const int* __restrict__ clssidx,
                                         const int* __restrict__ clscnt,
                                         const int* __restrict__ clsoff,
                                         const float4* __restrict__ cbox,
                                         const float* __restrict__ cscore,
                                         const int* __restrict__ clabel,
                                         float* __restrict__ out) {
    int b = blockIdx.x;
    int lane = threadIdx.x;
    __shared__ ull sKeep[32];
    if (lane < 32) sKeep[lane] = 0ull;
    __syncthreads();

    // map per-class alive bits back to sorted-position bitmap (LDS atomics only)
    for (int c = lane; c < NFG; c += 64) {
        int n = clscnt[b * 96 + c];
        if (n <= 0) continue;
        if (n > CLSCAP) n = CLSCAP;
        int W = (n + 63) >> 6;
        int base = b * TOPK + clsoff[b * 96 + c];
        for (int w = 0; w < W; ++w) {
            ull bits = keepcls[(size_t)(b * 96 + c) * 8 + w];
            while (bits) {
                int s = __builtin_ctzll(bits); bits &= bits - 1;
                int sidx = clssidx[base + (w << 6) + s];
                atomicOr(&sKeep[sidx >> 6], 1ull << (sidx & 63));
            }
        }
    }
    __syncthreads();

    // lane owns candidates j in [lane*32, lane*32+32)
    unsigned m = (unsigned)(sKeep[lane >> 1] >> ((lane & 1) << 5));

    int cntk = __popc(m);
    int pre = cntk;
    #pragma unroll
    for (int o = 1; o < 64; o <<= 1) {
        int v = __shfl_up(pre, o);
        if (lane >= o) pre += v;
    }
    int total = __shfl(pre, 63);
    int excl = pre - cntk;

    unsigned mm = m;
    while (mm) {
        int t = __builtin_ctz(mm);
        mm &= mm - 1;
        int rank = excl++;
        if (rank < DETS) {
            int j = lane * 32 + t;
            int g = b * TOPK + j;
            float4 bx = cbox[g];
            *reinterpret_cast<float4*>(out + ((size_t)b * DETS + rank) * 4) = bx;
            out[NIMG * DETS * 4 + b * DETS + rank] = cscore[g];
            out[NIMG * DETS * 5 + b * DETS + rank] = (float)clabel[g];
        }
    }
    int kept100 = (total < DETS) ? total : DETS;
    int F = DETS - kept100;
    if (F > 0) {
        unsigned zm = ~m;
        int zc = __popc(zm);
        int zpre = zc;
        #pragma unroll
        for (int o = 1; o < 64; o <<= 1) {
            int v = __shfl_up(zpre, o);
            if (lane >= o) zpre += v;
        }
        int zexcl = zpre - zc;
        while (zm) {
            int t = __builtin_ctz(zm);
            zm &= zm - 1;
            int zr = zexcl++;
            if (zr < F) {
                int j = lane * 32 + t;
                int g = b * TOPK + j;
                float4 bx = cbox[g];
                int rank = kept100 + zr;
                *reinterpret_cast<float4*>(out + ((size_t)b * DETS + rank) * 4) = bx;
                out[NIMG * DETS * 4 + b * DETS + rank] = -1.0f;
                out[NIMG * DETS * 5 + b * DETS + rank] = (float)clabel[g];
            }
        }
    }
}

// ---------------- launch ----------------
extern "C" void kernel_launch(void* const* d_in, const int* in_sizes, int n_in,
                              void* d_out, int out_size, void* d_ws, size_t ws_size,
                              hipStream_t stream) {
    const float* logits = (const float*)d_in[0];   // [16000, 91]
    const float* reg    = (const float*)d_in[1];   // [16000, 364]
    const float* props  = (const float*)d_in[2];   // [8, 2000, 4]
    float* out = (float*)d_out;                    // boxes(3200) | scores(800) | labels(800)
    char* ws = (char*)d_ws;

    int* cntv   = (int*)(ws + OFF_CNT);
    ull* vbm2   = (ull*)(ws + OFF_VBM);
    ull* ck     = (ull*)(ws + OFF_CK);
    float4* cbox   = (float4*)(ws + OFF_CBOX);
    float*  cscor  = (float*)(ws + OFF_CSCOR);
    int*    clab   = (int*)(ws + OFF_CLAB);
    float4* clsbox = (float4*)(ws + OFF_CLSBOX);
    float*  clsar  = (float*)(ws + OFF_CLSAR);
    int*    clssx  = (int*)(ws + OFF_CLSSX);
    int*    clscnt = (int*)(ws + OFF_CLSCNT);
    int*    clsoff = (int*)(ws + OFF_CLSOFF);
    ull*    keepcls= (ull*)(ws + OFF_KCLS);

    hipMemsetAsync(ws, 0, 2048, stream);   // zero the padded counters only
    hipLaunchKernelGGL(kA, dim3(NROW / 16), dim3(1024), 0, stream,
                       logits, reg, props, ck, cntv, vbm2);
    hipLaunchKernelGGL(kB, dim3(NIMG), dim3(1024), 0, stream,
                       ck, cntv, vbm2, reg, props, cbox, cscor, clab,
                       clsbox, clsar, clssx, clscnt, clsoff);
    hipLaunchKernelGGL(kN, dim3(NIMG * NFG), dim3(64), 0, stream,
                       clsbox, clsar, clscnt, clsoff, keepcls);
    hipLaunchKernelGGL(kE, dim3(NIMG), dim3(64), 0, stream,
                       keepcls, clssx, clscnt, clsoff, cbox, cscor, clab, out);
}

// Round 12
// 128.077 us; speedup vs baseline: 1.2465x; 1.0914x over previous
//
#include <hip/hip_runtime.h>
#include <cstdint>
#include <cstddef>

// ---------------- problem constants ----------------
#define NIMG   8
#define NPROP  2000
#define NCLS   91
#define NFG    90
#define NROW   (NIMG * NPROP)      // 16000
#define TOPK   2048
#define DETS   100
#define CKCAP  32768
#define KREGS  12                  // register-resident keys/thread (12*1024=12288)
#define CLSCAP 512                 // max candidates per (image,class) handled by kN

#define IMG_Wf 1333.0f
#define IMG_Hf 800.0f
#define SCORE_TH 0.05f
#define MINSZ    0.01f
#define NMS_TH   0.5f
#define CLIPV    4.135166556742356f   // log(1000/16) rounded to f32
#define ORD_NEG1 0x407FFFFFu          // ford(-1.0f)
#define PADKEY   (((ull)ORD_NEG1 << 32) | 0xFFFFFFFFull)

typedef unsigned long long ull;

// ---------------- workspace layout (bytes) ----------------
// zeroed region [0, 2048): cntv (8 counters, 256B apart)
static const size_t OFF_CNT    = 0;                                  // 2048
static const size_t OFF_VBM    = 4096;                               // 16000*2*8
static const size_t OFF_CK     = 262144;                             // 8*32768*8
static const size_t OFF_CBOX   = OFF_CK    + (size_t)NIMG*CKCAP*8;   // 8*2048*16
static const size_t OFF_CSCOR  = OFF_CBOX  + (size_t)NIMG*TOPK*16;   // 8*2048*4
static const size_t OFF_CLAB   = OFF_CSCOR + (size_t)NIMG*TOPK*4;    // 8*2048*4
static const size_t OFF_CLSBOX = OFF_CLAB  + (size_t)NIMG*TOPK*4;    // 8*2048*16
static const size_t OFF_CLSAR  = OFF_CLSBOX+ (size_t)NIMG*TOPK*16;   // 8*2048*4
static const size_t OFF_CLSKEY = OFF_CLSAR + (size_t)NIMG*TOPK*4;    // 8*2048*8
static const size_t OFF_KEEPF  = OFF_CLSKEY+ (size_t)NIMG*TOPK*8;    // 8*2048*4
static const size_t OFF_CLSCNT = OFF_KEEPF + (size_t)NIMG*TOPK*4;    // 8*96*4
static const size_t OFF_CLSOFF = OFF_CLSCNT+ (size_t)NIMG*96*4;      // 8*96*4

// ---------------- helpers ----------------
__device__ __forceinline__ unsigned ford(float f) {
    unsigned u = __float_as_uint(f);
    return (u & 0x80000000u) ? ~u : (u | 0x80000000u);
}
__device__ __forceinline__ float fordinv(unsigned x) {
    return (x & 0x80000000u) ? __uint_as_float(x & 0x7FFFFFFFu)
                             : __uint_as_float(~x);
}

// exact op-for-op mirror of reference _decode + clip (no FMA contraction)
__device__ __forceinline__ float4 decode_clip(float4 p, float4 r) {
    float w  = __fsub_rn(p.z, p.x);
    float h  = __fsub_rn(p.w, p.y);
    float cx = __fadd_rn(p.x, __fmul_rn(0.5f, w));
    float cy = __fadd_rn(p.y, __fmul_rn(0.5f, h));
    float dx = __fdiv_rn(r.x, 10.0f);
    float dy = __fdiv_rn(r.y, 10.0f);
    float dw = fminf(__fdiv_rn(r.z, 5.0f), CLIPV);
    float dh = fminf(__fdiv_rn(r.w, 5.0f), CLIPV);
    float pcx = __fadd_rn(__fmul_rn(dx, w), cx);
    float pcy = __fadd_rn(__fmul_rn(dy, h), cy);
    float pw  = __fmul_rn(expf(dw), w);
    float ph  = __fmul_rn(expf(dh), h);
    float x1 = __fsub_rn(pcx, __fmul_rn(0.5f, pw));
    float y1 = __fsub_rn(pcy, __fmul_rn(0.5f, ph));
    float x2 = __fadd_rn(pcx, __fmul_rn(0.5f, pw));
    float y2 = __fadd_rn(pcy, __fmul_rn(0.5f, ph));
    float4 o;
    o.x = fminf(fmaxf(x1, 0.0f), IMG_Wf);
    o.y = fminf(fmaxf(y1, 0.0f), IMG_Hf);
    o.z = fminf(fmaxf(x2, 0.0f), IMG_Wf);
    o.w = fminf(fmaxf(y2, 0.0f), IMG_Hf);
    return o;
}

// bitonic wave-local phase with payload: thread owns elements (base, base+1)
__device__ __forceinline__ void wl_pair(ull& a, ull& b, int& pa, int& pb,
                                        int l, int base, int k, int jmax) {
    bool desc = ((base & k) == 0);
    for (int j = jmax; j >= 2; j >>= 1) {
        int pl = l ^ (j >> 1);
        bool lower = ((base & j) == 0);
        ull qa = __shfl(a, pl), qb = __shfl(b, pl);
        int ra = __shfl(pa, pl), rb = __shfl(pb, pl);
        bool km = (desc == lower);
        bool ta = km ? (a > qa) : (a < qa);
        a = ta ? a : qa;  pa = ta ? pa : ra;
        bool tb = km ? (b > qb) : (b < qb);
        b = tb ? b : qb;  pb = tb ? pb : rb;
    }
    bool sw = ((a < b) == desc);
    if (sw) { ull t = a; a = b; b = t; int tp = pa; pa = pb; pb = tp; }
}

// ============ kernel A: softmax + decode + valid -> compacted keys + row bitmap ============
__global__ __launch_bounds__(1024) void kA(const float* __restrict__ logits,
                                           const float* __restrict__ reg,
                                           const float* __restrict__ props,
                                           ull* __restrict__ ck,
                                           int* __restrict__ cntv,
                                           ull* __restrict__ vbm2) {
    int warp = threadIdx.x >> 6;
    int lane = threadIdx.x & 63;
    int row  = blockIdx.x * 16 + warp;
    int b = row / NPROP;                 // uniform within block
    int n = row - b * NPROP;
    const float* lrow = logits + (size_t)row * NCLS;

    float xa = lrow[lane];
    float xb = (lane < 27) ? lrow[64 + lane] : -INFINITY;
    float mx = fmaxf(xa, xb);
    #pragma unroll
    for (int o = 32; o; o >>= 1) mx = fmaxf(mx, __shfl_xor(mx, o));
    float ea = expf(__fsub_rn(xa, mx));
    float eb = (lane < 27) ? expf(__fsub_rn(xb, mx)) : 0.0f;
    float s  = __fadd_rn(ea, eb);
    #pragma unroll
    for (int o = 32; o; o >>= 1) s = __fadd_rn(s, __shfl_xor(s, o));

    const float4 p = *reinterpret_cast<const float4*>(props + (size_t)row * 4);

    __shared__ int sCnt[32];
    __shared__ int sExc[32];
    __shared__ int sBase;

    ull rowmask[2];
    bool validA[2];
    ull keyA[2];
    #pragma unroll
    for (int it = 0; it < 2; ++it) {
        int c = (it == 0) ? (1 + lane) : (65 + lane);
        bool active = (it == 0) ? true : (lane < 26);
        bool valid = false;
        ull key = 0;
        if (active) {
            float lg = lrow[c];
            float score = __fdiv_rn(expf(__fsub_rn(lg, mx)), s);
            float4 r4 = *reinterpret_cast<const float4*>(
                reg + ((size_t)row * NCLS + c) * 4);
            float4 bx = decode_clip(p, r4);
            float bw = __fsub_rn(bx.z, bx.x);
            float bh = __fsub_rn(bx.w, bx.y);
            valid = (score > SCORE_TH) && (bw >= MINSZ) && (bh >= MINSZ);
            int offidx = n * NFG + (c - 1);
            key = ((ull)ford(score) << 32) |
                  (ull)(0xFFFFFFFFu - (unsigned)offidx);
        }
        ull bal = __ballot(valid);
        rowmask[it] = bal;
        validA[it] = valid;
        keyA[it] = key;
        if (lane == 0) sCnt[warp * 2 + it] = __popcll(bal);
    }
    __syncthreads();
    if (warp == 0) {
        int c = (lane < 32) ? sCnt[lane] : 0;
        int p2 = c;
        #pragma unroll
        for (int o = 1; o < 32; o <<= 1) {
            int v = __shfl_up(p2, o);
            if (lane >= o) p2 += v;
        }
        if (lane == 31) sBase = atomicAdd(&cntv[b * 64], p2);
        if (lane < 32) sExc[lane] = p2 - c;
    }
    __syncthreads();
    int base = sBase;
    #pragma unroll
    for (int it = 0; it < 2; ++it) {
        if (validA[it]) {
            int slot = base + sExc[warp * 2 + it] +
                       __popcll(rowmask[it] & ((1ull << lane) - 1ull));
            if (slot < CKCAP)
                ck[(size_t)b * CKCAP + slot] = keyA[it];
        }
    }
    if (lane == 0) {
        vbm2[(size_t)row * 2]     = rowmask[0];
        vbm2[(size_t)row * 2 + 1] = rowmask[1];
    }
}

// ============ kernel B: exact top-2048 select + decode + unsorted class bucketing ============
__global__ __launch_bounds__(1024) void kB(const ull* __restrict__ ck,
                                           const int* __restrict__ cntv,
                                           const ull* __restrict__ vbm2,
                                           const float* __restrict__ reg,
                                           const float* __restrict__ props,
                                           float4* __restrict__ cbox,
                                           float* __restrict__ cscore,
                                           int* __restrict__ clabel,
                                           float4* __restrict__ clsbox,
                                           float* __restrict__ clsarea,
                                           ull* __restrict__ clskey,
                                           int* __restrict__ keepflag,
                                           int* __restrict__ clscnt,
                                           int* __restrict__ clsoff) {
    int b = blockIdx.x;
    int tid = threadIdx.x;
    int lane = tid & 63, warp = tid >> 6;
    __shared__ ull sk[TOPK];
    __shared__ unsigned histw[16 * 256];    // per-wave histograms (16 KB)
    __shared__ unsigned wtot4[4];
    __shared__ ull sP;
    __shared__ int sRem, sCnt, sDone, sInv, sVT;
    __shared__ float sMax[16];
    __shared__ float sM1;
    __shared__ int rex[NPROP];
    __shared__ int wsum[16];
    __shared__ int ccnt[96], cplc[96], coff[96];

    int cnt = cntv[b * 64];
    if (cnt > CKCAP) cnt = CKCAP;
    const ull* K = ck + (size_t)b * CKCAP;

    if (cnt >= TOPK) {
        // ---- load keys into registers (coalesced, once) ----
        ull kreg[KREGS];
        #pragma unroll
        for (int r = 0; r < KREGS; ++r) {
            int i = tid + (r << 10);
            kreg[r] = (i < cnt) ? K[i] : 0ull;
        }
        // ---- 8x8-bit radix select with short-circuit (keys distinct) ----
        ull P = 0; int rem = TOPK;
        for (int pass = 7; pass >= 0; --pass) {
            int sh = pass * 8;
            *reinterpret_cast<uint4*>(&histw[tid * 4]) = make_uint4(0, 0, 0, 0);
            __syncthreads();
            ull pmask = (pass == 7) ? 0ull : (~0ull << (sh + 8));
            unsigned* hw = &histw[warp << 8];
            #pragma unroll
            for (int r = 0; r < KREGS; ++r) {
                int i = tid + (r << 10);
                if (i < cnt && (kreg[r] & pmask) == P)
                    atomicAdd(&hw[(unsigned)(kreg[r] >> sh) & 255u], 1u);
            }
            for (int i = (KREGS << 10) + tid; i < cnt; i += 1024) {   // rare tail
                ull k2 = K[i];
                if ((k2 & pmask) == P)
                    atomicAdd(&hw[(unsigned)(k2 >> sh) & 255u], 1u);
            }
            __syncthreads();
            unsigned x = 0, pfx = 0;
            if (tid < 256) {
                int d = 255 - tid;
                #pragma unroll
                for (int w = 0; w < 16; ++w) x += histw[(w << 8) + d];
                pfx = x;
                #pragma unroll
                for (int o = 1; o < 64; o <<= 1) {
                    unsigned v = __shfl_up(pfx, o);
                    if (lane >= o) pfx += v;
                }
                if (lane == 63) wtot4[tid >> 6] = pfx;
            }
            __syncthreads();
            if (tid < 256) {
                int d = 255 - tid;
                int ws = tid >> 6;
                unsigned add = 0;
                if (ws > 0) add += wtot4[0];
                if (ws > 1) add += wtot4[1];
                if (ws > 2) add += wtot4[2];
                unsigned pi   = pfx + add;    // suffixIncl(d)
                unsigned excl = pi - x;       // suffixExcl(d)
                if (x && excl < (unsigned)rem && pi >= (unsigned)rem) {
                    sP = P | ((ull)(unsigned)d << sh);
                    int nr = rem - (int)excl;
                    sRem = nr;
                    sDone = ((int)x == nr) ? 1 : 0;   // whole bin selected -> exact
                }
            }
            __syncthreads();
            P = sP; rem = sRem;
            if (sDone) break;      // threshold exact with remaining low bits zero
        }
        if (tid == 0) sCnt = 0;
        __syncthreads();
        // ---- wave-aggregated compaction from registers (unsorted) ----
        #pragma unroll
        for (int r = 0; r < KREGS; ++r) {
            int i = tid + (r << 10);
            bool sel = (i < cnt) && (kreg[r] >= P);
            ull bal = __ballot(sel);
            int cw = __popcll(bal);
            if (cw) {
                int ldr = __ffsll((long long)bal) - 1;
                int bw = 0;
                if (lane == ldr) bw = atomicAdd(&sCnt, cw);
                bw = __shfl(bw, ldr);
                if (sel) {
                    int pos = bw + __popcll(bal & ((1ull << lane) - 1ull));
                    if (pos < TOPK) sk[pos] = kreg[r];
                }
            }
        }
        for (int i = (KREGS << 10) + tid; i < cnt; i += 1024) {       // rare tail
            ull k2 = K[i];
            bool sel = (k2 >= P);
            ull bal = __ballot(sel);
            int cw = __popcll(bal);
            if (cw) {
                int ldr = __ffsll((long long)bal) - 1;
                int bw = 0;
                if (lane == ldr) bw = atomicAdd(&sCnt, cw);
                bw = __shfl(bw, ldr);
                if (sel) {
                    int pos = bw + __popcll(bal & ((1ull << lane) - 1ull));
                    if (pos < TOPK) sk[pos] = k2;
                }
            }
        }
        __syncthreads();
        int fc = sCnt;
        for (int i = fc + tid; i < TOPK; i += 1024) sk[i] = PADKEY;
    } else {
        // take all valid + fill with smallest-index invalid (score -1, ascending idx)
        for (int i = tid; i < cnt; i += 1024) sk[i] = K[i];
        int F = TOPK - cnt;
        const ull* V = vbm2 + (size_t)b * NPROP * 2;
        int r0 = 2 * tid, r1 = r0 + 1;
        int v0 = 0, v1 = 0;
        if (r0 < NPROP) v0 = NFG - __popcll(V[r0 * 2]) - __popcll(V[r0 * 2 + 1]);
        if (r1 < NPROP) v1 = NFG - __popcll(V[r1 * 2]) - __popcll(V[r1 * 2 + 1]);
        int s2 = v0 + v1;
        int pfx = s2;
        #pragma unroll
        for (int o = 1; o < 64; o <<= 1) {
            int t = __shfl_up(pfx, o);
            if (lane >= o) pfx += t;
        }
        if (lane == 63) wsum[warp] = pfx;
        __syncthreads();
        if (tid == 0) {
            int a = 0;
            for (int w = 0; w < 16; ++w) { int t = wsum[w]; wsum[w] = a; a += t; }
        }
        __syncthreads();
        int excl = pfx - s2 + wsum[warp];
        if (r0 < NPROP) rex[r0] = excl;
        if (r1 < NPROP) rex[r1] = excl + v0;
        __syncthreads();
        for (int r = tid; r < NPROP; r += 1024) {
            int e = rex[r];
            if (e < F) {
                ull m0 = V[r * 2], m1 = V[r * 2 + 1];
                int rank = e;
                ull inv = ~m0;
                while (inv && rank < F) {
                    int cb = __builtin_ctzll(inv); inv &= inv - 1;
                    unsigned idx = (unsigned)(r * NFG + cb);
                    sk[cnt + rank] = ((ull)ORD_NEG1 << 32) | (ull)(0xFFFFFFFFu - idx);
                    ++rank;
                }
                inv = (~m1) & ((1ull << 26) - 1ull);
                while (inv && rank < F) {
                    int cb = __builtin_ctzll(inv); inv &= inv - 1;
                    unsigned idx = (unsigned)(r * NFG + 64 + cb);
                    sk[cnt + rank] = ((ull)ORD_NEG1 << 32) | (ull)(0xFFFFFFFFu - idx);
                    ++rank;
                }
            }
        }
    }
    __syncthreads();

    // ---- decode the 2048 selected candidates (unsorted storage order) ----
    float lmax = 0.0f;
    float4 myb[2]; int myl[2]; float mys[2]; bool vkA[2]; ull kkA[2];
    #pragma unroll
    for (int r = 0; r < 2; ++r) {
        int pos0 = tid + r * 1024;
        ull k = sk[pos0];
        unsigned idx = 0xFFFFFFFFu - (unsigned)(k & 0xFFFFFFFFu);
        float score = fordinv((unsigned)(k >> 32));
        int n = (int)(idx / NFG), c = (int)(idx % NFG);     // label = c+1
        int row = b * NPROP + n;
        float4 p  = *reinterpret_cast<const float4*>(props + (size_t)row * 4);
        float4 r4 = *reinterpret_cast<const float4*>(
            reg + ((size_t)row * NCLS + (c + 1)) * 4);
        float4 bx = decode_clip(p, r4);
        myb[r] = bx; myl[r] = c + 1; mys[r] = score; kkA[r] = k;
        vkA[r] = (((unsigned)(k >> 32)) != ORD_NEG1);
        lmax = fmaxf(lmax, fmaxf(fmaxf(bx.x, bx.y), fmaxf(bx.z, bx.w)));
    }
    #pragma unroll
    for (int o = 32; o; o >>= 1) lmax = fmaxf(lmax, __shfl_xor(lmax, o));
    if ((tid & 63) == 0) sMax[tid >> 6] = lmax;
    if (tid < 96) { ccnt[tid] = 0; cplc[tid] = 0; }
    if (tid == 0) sInv = 0;
    __syncthreads();
    if (tid == 0) {
        float v = sMax[0];
        for (int i = 1; i < 16; ++i) v = fmaxf(v, sMax[i]);
        sM1 = __fadd_rn(v, 1.0f);            // jnp.max(cand_boxes) + 1.0
    }
    // phase 1: class counts
    #pragma unroll
    for (int r = 0; r < 2; ++r)
        if (vkA[r]) atomicAdd(&ccnt[myl[r] - 1], 1);
    __syncthreads();
    if (tid == 0) {
        int a = 0;
        for (int c2 = 0; c2 < NFG; ++c2) { coff[c2] = a; a += ccnt[c2]; }
        sVT = a;
    }
    __syncthreads();
    float m1 = sM1;
    int validTot = sVT;
    // phase 2: placement (order within class arbitrary; kN sorts by key)
    #pragma unroll
    for (int r = 0; r < 2; ++r) {
        int slot;
        if (vkA[r]) {
            int cl = myl[r] - 1;
            slot = coff[cl] + atomicAdd(&cplc[cl], 1);
        } else {
            slot = validTot + atomicAdd(&sInv, 1);
        }
        int g2 = b * TOPK + slot;
        float off = __fmul_rn((float)myl[r], m1);
        float4 ob;
        ob.x = __fadd_rn(myb[r].x, off);
        ob.y = __fadd_rn(myb[r].y, off);
        ob.z = __fadd_rn(myb[r].z, off);
        ob.w = __fadd_rn(myb[r].w, off);
        float area = __fmul_rn(__fsub_rn(ob.z, ob.x), __fsub_rn(ob.w, ob.y));
        clsbox[g2] = ob; clsarea[g2] = area; clskey[g2] = kkA[r];
        cbox[g2] = myb[r]; cscore[g2] = mys[r]; clabel[g2] = myl[r];
        keepflag[g2] = 0;        // kN overwrites valid slots; invalid stay 0
    }
    if (tid < NFG) {
        clscnt[b * 96 + tid] = ccnt[tid];
        clsoff[b * 96 + tid] = coff[tid];
    }
}

// ============ kernel N: per-(image,class) key-sort + greedy NMS -> keepflag ============
__global__ __launch_bounds__(64) void kN(const float4* __restrict__ clsbox,
                                         const float* __restrict__ clsarea,
                                         const ull* __restrict__ clskey,
                                         const int* __restrict__ clscnt,
                                         const int* __restrict__ clsoff,
                                         int* __restrict__ keepflag) {
    int bc = blockIdx.x;
    int b = bc / NFG, c = bc - b * NFG;
    int n = clscnt[b * 96 + c];
    if (n <= 0) return;
    if (n > CLSCAP) n = CLSCAP;   // unreachable at observed densities
    int lane = threadIdx.x;
    int base = b * TOPK + clsoff[b * 96 + c];

    if (n <= 64) {
        // sort (key desc, payload slot) via shfl bitonic, pads sink (keys tiny)
        ull key = (lane < n) ? clskey[base + lane] : (ull)lane;
        int slot = (lane < n) ? (base + lane) : -1;
        #pragma unroll
        for (int k = 2; k <= 64; k <<= 1) {
            #pragma unroll
            for (int j = k >> 1; j > 0; j >>= 1) {
                int pl = lane ^ j;
                ull qk = __shfl(key, pl);
                int qs = __shfl(slot, pl);
                bool desc = ((lane & k) == 0);
                bool lower = ((lane & j) == 0);
                bool km = (desc == lower);
                bool keepown = km ? (key > qk) : (key < qk);
                key = keepown ? key : qk;
                slot = keepown ? slot : qs;
            }
        }
        float4 b0; float a0 = 0.0f;
        if (slot >= 0) { b0 = clsbox[slot]; a0 = clsarea[slot]; }
        ull alive = (n == 64) ? ~0ull : ((1ull << n) - 1ull);
        #pragma unroll 1
        for (int i = 0; i < n; ++i) {
            if (!((alive >> i) & 1ull)) continue;
            float bix = __shfl(b0.x, i), biy = __shfl(b0.y, i);
            float biz = __shfl(b0.z, i), biw = __shfl(b0.w, i);
            float ai2 = __shfl(a0, i);
            bool sup = false;
            if (lane < n && lane > i) {
                float lt0 = fmaxf(bix, b0.x), lt1 = fmaxf(biy, b0.y);
                float rb0 = fminf(biz, b0.z), rb1 = fminf(biw, b0.w);
                float w0 = fmaxf(__fsub_rn(rb0, lt0), 0.0f);
                float w1 = fmaxf(__fsub_rn(rb1, lt1), 0.0f);
                float inter = __fmul_rn(w0, w1);
                if (inter > 0.0f) {
                    float un = __fsub_rn(__fadd_rn(ai2, a0), inter);
                    sup = (__fdiv_rn(inter, un) > NMS_TH);
                }
            }
            alive &= ~__ballot(sup);
        }
        if (lane < n) keepflag[slot] = (int)((alive >> lane) & 1ull);
        return;
    }

    // ---- cold path: 64 < n <= 512 (statistically unreachable) ----
    __shared__ ull  skey[CLSCAP];
    __shared__ int  sslot[CLSCAP];
    __shared__ float4 sbox[CLSCAP];
    __shared__ float  sar[CLSCAP];
    __shared__ ull    smask[CLSCAP * 8];
    __shared__ ull    salive[8];
    for (int t = lane; t < n; t += 64) {
        skey[t] = clskey[base + t];
        sslot[t] = base + t;
    }
    __syncthreads();
    // selection sort descending (wave-parallel argmax per step)
    for (int r = 0; r < n - 1; ++r) {
        ull best = 0; int bi = -1;
        for (int t = r + lane; t < n; t += 64)
            if (skey[t] > best) { best = skey[t]; bi = t; }
        #pragma unroll
        for (int o = 32; o; o >>= 1) {
            ull ob = __shfl_xor(best, o);
            int oi = __shfl_xor(bi, o);
            if (ob > best) { best = ob; bi = oi; }
        }
        if (lane == 0 && bi != r) {
            ull tk = skey[r]; skey[r] = skey[bi]; skey[bi] = tk;
            int ts = sslot[r]; sslot[r] = sslot[bi]; sslot[bi] = ts;
        }
        __syncthreads();
    }
    for (int t = lane; t < n; t += 64) {
        sbox[t] = clsbox[sslot[t]];
        sar[t]  = clsarea[sslot[t]];
    }
    __syncthreads();
    int W = (n + 63) >> 6;
    for (int i = lane; i < n; i += 64) {
        float4 a = sbox[i]; float ai = sar[i];
        for (int w = 0; w < W; ++w) {
            ull word = 0;
            int jn = n - (w << 6); if (jn > 64) jn = 64;
            for (int s = 0; s < jn; ++s) {
                int j = (w << 6) + s;
                if (j > i) {
                    float4 cc = sbox[j];
                    float lt0 = fmaxf(a.x, cc.x), lt1 = fmaxf(a.y, cc.y);
                    float rb0 = fminf(a.z, cc.z), rb1 = fminf(a.w, cc.w);
                    float w0 = fmaxf(__fsub_rn(rb0, lt0), 0.0f);
                    float w1 = fmaxf(__fsub_rn(rb1, lt1), 0.0f);
                    float inter = __fmul_rn(w0, w1);
                    if (inter > 0.0f) {
                        float un = __fsub_rn(__fadd_rn(ai, sar[j]), inter);
                        if (__fdiv_rn(inter, un) > NMS_TH) word |= (1ull << s);
                    }
                }
            }
            smask[i * W + w] = word;
        }
    }
    __syncthreads();
    ull alive = 0;
    if (lane < W) {
        int rem = n - (lane << 6);
        alive = (rem >= 64) ? ~0ull : ((1ull << rem) - 1ull);
    }
    for (int i = 0; i < n; ++i) {
        ull aw = __shfl(alive, i >> 6);
        if ((aw >> (i & 63)) & 1ull) {
            if (lane < W) alive &= ~smask[i * W + lane];
        }
    }
    if (lane < W) salive[lane] = alive;
    __syncthreads();
    for (int t = lane; t < n; t += 64)
        keepflag[sslot[t]] = (int)((salive[t >> 6] >> (t & 63)) & 1ull);
}

// ============ kernel E: two-segment top-100 selection + emit ============
__global__ __launch_bounds__(1024) void kE(const int* __restrict__ keepflag,
                                           const ull* __restrict__ clskey,
                                           const float4* __restrict__ cbox,
                                           const float* __restrict__ cscore,
                                           const int* __restrict__ clabel,
                                           float* __restrict__ out) {
    int b = blockIdx.x;
    int tid = threadIdx.x;
    int lane = tid & 63, warp = tid >> 6;
    __shared__ ull kk[TOPK];
    __shared__ int ks[TOPK];
    __shared__ unsigned histw[16 * 256];
    __shared__ unsigned wtot4[4];
    __shared__ ull sP;
    __shared__ int sRem, sDone, sK, sFC;
    __shared__ ull fkey[128];
    __shared__ int fslot[128];

    const ull* KY = clskey + (size_t)b * TOPK;
    const int* KF = keepflag + (size_t)b * TOPK;

    int emitted = 0;
    #pragma unroll 1
    for (int seg = 0; seg < 2; ++seg) {
        __syncthreads();
        if (tid == 0) sK = 0;
        __syncthreads();
        if (emitted < DETS) {
            for (int s = tid; s < TOPK; s += 1024) {
                bool f = (seg == 0) ? (KF[s] != 0) : (KF[s] == 0);
                ull key = KY[s];
                ull bal = __ballot(f);
                int cw = __popcll(bal);
                if (cw) {
                    int ldr = __ffsll((long long)bal) - 1;
                    int bw = 0;
                    if (lane == ldr) bw = atomicAdd(&sK, cw);
                    bw = __shfl(bw, ldr);
                    if (f) {
                        int p = bw + __popcll(bal & ((1ull << lane) - 1ull));
                        kk[p] = key; ks[p] = s;
                    }
                }
            }
        }
        __syncthreads();
        int K = sK;
        int T = DETS - emitted;
        if (T > K) T = K;
        if (emitted < DETS && K > 0) {
            ull P = 0;
            if (K > T) {
                int rem = T;
                for (int pass = 7; pass >= 0; --pass) {
                    int sh = pass * 8;
                    *reinterpret_cast<uint4*>(&histw[tid * 4]) = make_uint4(0, 0, 0, 0);
                    __syncthreads();
                    ull pmask = (pass == 7) ? 0ull : (~0ull << (sh + 8));
                    unsigned* hw = &histw[warp << 8];
                    for (int i = tid; i < K; i += 1024) {
                        ull k2 = kk[i];
                        if ((k2 & pmask) == P)
                            atomicAdd(&hw[(unsigned)(k2 >> sh) & 255u], 1u);
                    }
                    __syncthreads();
                    unsigned x = 0, pfx = 0;
                    if (tid < 256) {
                        int d = 255 - tid;
                        #pragma unroll
                        for (int w = 0; w < 16; ++w) x += histw[(w << 8) + d];
                        pfx = x;
                        #pragma unroll
                        for (int o = 1; o < 64; o <<= 1) {
                            unsigned v = __shfl_up(pfx, o);
                            if (lane >= o) pfx += v;
                        }
                        if (lane == 63) wtot4[tid >> 6] = pfx;
                    }
                    __syncthreads();
                    if (tid < 256) {
                        int d = 255 - tid;
                        int ws = tid >> 6;
                        unsigned add = 0;
                        if (ws > 0) add += wtot4[0];
                        if (ws > 1) add += wtot4[1];
                        if (ws > 2) add += wtot4[2];
                        unsigned pi   = pfx + add;
                        unsigned excl = pi - x;
                        if (x && excl < (unsigned)rem && pi >= (unsigned)rem) {
                            sP = P | ((ull)(unsigned)d << sh);
                            int nr = rem - (int)excl;
                            sRem = nr;
                            sDone = ((int)x == nr) ? 1 : 0;
                        }
                    }
                    __syncthreads();
                    P = sP; rem = sRem;
                    if (sDone) break;
                }
            }
            if (tid == 0) sFC = 0;
            __syncthreads();
            for (int i = tid; i < K; i += 1024) {
                ull k2 = kk[i];
                bool sel = (k2 >= P);
                ull bal = __ballot(sel);
                int cw = __popcll(bal);
                if (cw) {
                    int ldr = __ffsll((long long)bal) - 1;
                    int bw = 0;
                    if (lane == ldr) bw = atomicAdd(&sFC, cw);
                    bw = __shfl(bw, ldr);
                    if (sel) {
                        int p2 = bw + __popcll(bal & ((1ull << lane) - 1ull));
                        if (p2 < T) { fkey[p2] = k2; fslot[p2] = ks[i]; }
                    }
                }
            }
            __syncthreads();
            int FC = sFC; if (FC > T) FC = T;
            for (int i = FC + tid; i < 128; i += 1024) { fkey[i] = 0; fslot[i] = -1; }
            __syncthreads();
            if (warp == 0) {
                int base2 = lane * 2;
                ull a = fkey[base2], bb = fkey[base2 + 1];
                int pa = fslot[base2], pb = fslot[base2 + 1];
                #pragma unroll
                for (int k = 2; k <= 128; k <<= 1)
                    wl_pair(a, bb, pa, pb, lane, base2, k,
                            (k >> 1) < 64 ? (k >> 1) : 64);
                #pragma unroll
                for (int e = 0; e < 2; ++e) {
                    int rnk = base2 + e;
                    ull kv = e ? bb : a;
                    int sl = e ? pb : pa;
                    (void)kv;
                    if (rnk < T && sl >= 0) {
                        int r2 = emitted + rnk;
                        int g = b * TOPK + sl;
                        float4 bx = cbox[g];
                        *reinterpret_cast<float4*>(out + ((size_t)b * DETS + r2) * 4) = bx;
                        out[NIMG * DETS * 4 + b * DETS + r2] =
                            (seg == 0) ? cscore[g] : -1.0f;
                        out[NIMG * DETS * 5 + b * DETS + r2] = (float)clabel[g];
                    }
                }
            }
            emitted += T;
        }
        __syncthreads();
    }
}

// ---------------- launch ----------------
extern "C" void kernel_launch(void* const* d_in, const int* in_sizes, int n_in,
                              void* d_out, int out_size, void* d_ws, size_t ws_size,
                              hipStream_t stream) {
    const float* logits = (const float*)d_in[0];   // [16000, 91]
    const float* reg    = (const float*)d_in[1];   // [16000, 364]
    const float* props  = (const float*)d_in[2];   // [8, 2000, 4]
    float* out = (float*)d_out;                    // boxes(3200) | scores(800) | labels(800)
    char* ws = (char*)d_ws;

    int* cntv   = (int*)(ws + OFF_CNT);
    ull* vbm2   = (ull*)(ws + OFF_VBM);
    ull* ck     = (ull*)(ws + OFF_CK);
    float4* cbox   = (float4*)(ws + OFF_CBOX);
    float*  cscor  = (float*)(ws + OFF_CSCOR);
    int*    clab   = (int*)(ws + OFF_CLAB);
    float4* clsbox = (float4*)(ws + OFF_CLSBOX);
    float*  clsar  = (float*)(ws + OFF_CLSAR);
    ull*    clskey = (ull*)(ws + OFF_CLSKEY);
    int*    keepf  = (int*)(ws + OFF_KEEPF);
    int*    clscnt = (int*)(ws + OFF_CLSCNT);
    int*    clsoff = (int*)(ws + OFF_CLSOFF);

    hipMemsetAsync(ws, 0, 2048, stream);   // zero the padded counters only
    hipLaunchKernelGGL(kA, dim3(NROW / 16), dim3(1024), 0, stream,
                       logits, reg, props, ck, cntv, vbm2);
    hipLaunchKernelGGL(kB, dim3(NIMG), dim3(1024), 0, stream,
                       ck, cntv, vbm2, reg, props, cbox, cscor, clab,
                       clsbox, clsar, clskey, keepf, clscnt, clsoff);
    hipLaunchKernelGGL(kN, dim3(NIMG * NFG), dim3(64), 0, stream,
                       clsbox, clsar, clskey, clscnt, clsoff, keepf);
    hipLaunchKernelGGL(kE, dim3(NIMG), dim3(1024), 0, stream,
                       keepf, clskey, cbox, cscor, clab, out);
}